// Round 6
// baseline (1569.284 us; speedup 1.0000x reference)
//
#include <hip/hip_runtime.h>
#include <hip/hip_bf16.h>
#include <math.h>

#define D_MODEL 256
#define NH 8
#define DFF 1024
#define NLAYERS 6
#define B_ 8
#define L_ 1024
#define NR (B_*L_)          // 8192 rows
#define TOPK 256            // L/4
#define LNEPS 1e-5f

typedef __attribute__((ext_vector_type(8))) short bf16x8;
typedef __attribute__((ext_vector_type(4))) float f32x4;

// ---------------- helpers ----------------
__device__ __forceinline__ float wsum(float v){
  #pragma unroll
  for(int o=32;o>0;o>>=1) v += __shfl_xor(v,o,64);
  return v;
}
__device__ __forceinline__ short f2bf(float x){
  unsigned u = __float_as_uint(x);
  u += 0x7fffu + ((u>>16)&1u);   // RNE (finite inputs only)
  return (short)(u>>16);
}
__device__ __forceinline__ float bf2f(short s){
  return __uint_as_float(((unsigned)(unsigned short)s)<<16);
}
// packed 2x f32 -> 2x bf16
__device__ __forceinline__ unsigned pk2bf(float a, float b){
  __hip_bfloat162 h = __float22bfloat162_rn(make_float2(a,b));
  unsigned u; __builtin_memcpy(&u, &h, 4);
  return u;
}
// bf16 raw bits -> 16-bit sortable key (order-isomorphic to float value)
__device__ __forceinline__ int sortkey(unsigned u){
  return (u & 0x8000u) ? (int)(u ^ 0xFFFFu) : (int)(u | 0x8000u);
}
// sortable key -> float value
__device__ __forceinline__ float kinvf(int k){
  unsigned u = (k & 0x8000) ? ((unsigned)k ^ 0x8000u) : ((unsigned)k ^ 0xFFFFu);
  return __uint_as_float(u << 16);
}
// async global->LDS, 16B per lane (dest = wave-uniform base + lane*16)
__device__ __forceinline__ void g2l(const short* g, short* l){
  __builtin_amdgcn_global_load_lds(
      (const __attribute__((address_space(1))) unsigned int*)g,
      (__attribute__((address_space(3))) unsigned int*)l,
      16, 0, 0);
}

// ---------------- embed: h = x@in_w + in_b + pe ----------------
__global__ __launch_bounds__(256) void embed_kernel(
    const float* __restrict__ x, const float* __restrict__ in_w,
    const float* __restrict__ in_b, float* __restrict__ h)
{
  int tid = blockIdx.x*256 + threadIdx.x;
  int n  = tid >> 6;
  int d0 = (tid & 63) << 2;
  int l  = n & (L_-1);
  float x0 = x[2*n], x1 = x[2*n+1];
  const float kf = -0.07195578415606394f;   // -ln(10000)/128
  float pe[4];
  #pragma unroll
  for(int ii=0; ii<2; ++ii){
    int i = (d0>>1) + ii;
    float dv  = expf((float)i * kf);
    float ang = (float)l * dv;
    pe[2*ii]   = sinf(ang);
    pe[2*ii+1] = cosf(ang);
  }
  float4 w0 = *(const float4*)(in_w + d0);
  float4 w1 = *(const float4*)(in_w + D_MODEL + d0);
  float4 bb = *(const float4*)(in_b + d0);
  float4 o;
  o.x = x0*w0.x + x1*w1.x + bb.x + pe[0];
  o.y = x0*w0.y + x1*w1.y + bb.y + pe[1];
  o.z = x0*w0.z + x1*w1.z + bb.z + pe[2];
  o.w = x0*w0.w + x1*w1.w + bb.w + pe[3];
  *(float4*)(h + (size_t)n*D_MODEL + d0) = o;
}

// ---------------- weight convert+transpose: WT[n][k] = bf16(W[k][n]) ----------------
__global__ __launch_bounds__(256) void wcvt(
    const float* __restrict__ W, short* __restrict__ WT, int N, int kshift)
{
  int idx = blockIdx.x*256 + threadIdx.x;
  int K = 1<<kshift;
  if (idx >= N*K) return;
  int n = idx >> kshift, k = idx & (K-1);
  WT[idx] = f2bf(W[(size_t)k*N + n]);
}

// ---------------- LayerNorm: wave per row ----------------
// OM: 0 = fp32 out, 2 = bf16 out only
template<int OM>
__global__ __launch_bounds__(256) void ln_kernel(
    const float* __restrict__ in, const float* __restrict__ g,
    const float* __restrict__ b, float* __restrict__ out,
    short* __restrict__ outb)
{
  int wave = threadIdx.x >> 6, lane = threadIdx.x & 63;
  int row = blockIdx.x*4 + wave;
  float4 v = ((const float4*)(in + (size_t)row*D_MODEL))[lane];
  float s  = v.x+v.y+v.z+v.w;
  float sq = v.x*v.x+v.y*v.y+v.z*v.z+v.w*v.w;
  s = wsum(s); sq = wsum(sq);
  float mean = s*(1.f/D_MODEL);
  float var  = sq*(1.f/D_MODEL) - mean*mean;
  float rstd = 1.f/sqrtf(var + LNEPS);
  float4 gv = ((const float4*)g)[lane];
  float4 bv = ((const float4*)b)[lane];
  float4 o;
  o.x = (v.x-mean)*rstd*gv.x + bv.x;
  o.y = (v.y-mean)*rstd*gv.y + bv.y;
  o.z = (v.z-mean)*rstd*gv.z + bv.z;
  o.w = (v.w-mean)*rstd*gv.w + bv.w;
  if (OM == 0){
    ((float4*)(out + (size_t)row*D_MODEL))[lane] = o;
  }
  if (OM == 2){
    uint2 pk; pk.x = pk2bf(o.x, o.y); pk.y = pk2bf(o.z, o.w);
    *(uint2*)(outb + (size_t)row*D_MODEL + lane*4) = pk;
  }
}

// ---------------- bf16 MFMA GEMM (round-4 config): 128x64 tile, BK=32 ----------------
// MODE 0: qkv epilogue (Q/K row-major bf16 + V^T bf16)
// MODE 2: Cb = bf16(acc + bias)
// MODE 3: Cf += acc + bias  (fp32 accumulate into h)
template<int MODE>
__global__ __launch_bounds__(256) void mfma_gemm(
    const short* __restrict__ A, const short* __restrict__ BT,
    const float* __restrict__ bias,
    float* __restrict__ Cf, short* __restrict__ Cb, short* __restrict__ Vt,
    int N, int K)
{
  __shared__ __align__(16) short As[128*32];   // 8 KB [m][k]
  __shared__ __align__(16) short Bs[64*32];    // 4 KB [n][k]
  const int t = threadIdx.x, wv = t>>6, lane = t&63;
  const int r16 = lane&15, quad = lane>>4;
  const int m0 = blockIdx.y*128, n0 = blockIdx.x*64;
  const int ia0 = wv*128 + lane, ia1 = ia0 + 64;
  const int ib  = wv*64 + lane;
  const short* Ab = A  + (size_t)m0*K;
  const short* Bb = BT + (size_t)n0*K;
  const f32x4 z = {0.f,0.f,0.f,0.f};
  f32x4 acc[2][4];
  #pragma unroll
  for (int i=0;i<2;++i)
    #pragma unroll
    for (int j=0;j<4;++j) acc[i][j] = z;

  for (int k0 = 0; k0 < K; k0 += 32){
    __syncthreads();
    g2l(Ab + (size_t)(ia0>>2)*K + k0 + (ia0&3)*8, As + ia0*8);
    g2l(Ab + (size_t)(ia1>>2)*K + k0 + (ia1&3)*8, As + ia1*8);
    g2l(Bb + (size_t)(ib>>2)*K  + k0 + (ib&3)*8,  Bs + ib*8);
    __syncthreads();
    bf16x8 af0 = *(const bf16x8*)(As + ((wv*32      + r16)*32 + quad*8));
    bf16x8 af1 = *(const bf16x8*)(As + ((wv*32 + 16 + r16)*32 + quad*8));
    bf16x8 bf[4];
    #pragma unroll
    for (int ct=0; ct<4; ++ct)
      bf[ct] = *(const bf16x8*)(Bs + ((ct*16 + r16)*32 + quad*8));
    #pragma unroll
    for (int ct=0; ct<4; ++ct){
      acc[0][ct] = __builtin_amdgcn_mfma_f32_16x16x32_bf16(af0, bf[ct], acc[0][ct], 0,0,0);
      acc[1][ct] = __builtin_amdgcn_mfma_f32_16x16x32_bf16(af1, bf[ct], acc[1][ct], 0,0,0);
    }
  }

  #pragma unroll
  for (int rt=0; rt<2; ++rt){
    const int mb = m0 + wv*32 + rt*16 + quad*4;
    #pragma unroll
    for (int ct=0; ct<4; ++ct){
      const int n = n0 + ct*16 + r16;
      const float bv = bias[n];
      if (MODE == 0){
        if (n < 512){                    // Q or K: qkbf[region*64+bh][l][d]
          int region = n>>8, hh = (n>>5)&7, d = n&31;
          #pragma unroll
          for (int r=0;r<4;++r){
            int l = mb + r;
            size_t base = (((size_t)(region*64 + (l>>10)*8 + hh))*1024 + (l&1023))*32 + d;
            Cb[base] = f2bf(acc[rt][ct][r] + bv);
          }
        } else {                         // V transposed: vT[bh][d][l]
          int dv = n - 512, hh = dv>>5, d = dv&31;
          int b = mb>>10, lloc = mb&1023;
          size_t base = (((size_t)(b*8 + hh))*32 + d)*1024 + lloc;
          uint2 pk;
          pk.x = pk2bf(acc[rt][ct][0] + bv, acc[rt][ct][1] + bv);
          pk.y = pk2bf(acc[rt][ct][2] + bv, acc[rt][ct][3] + bv);
          *(uint2*)(Vt + base) = pk;
        }
      } else {
        #pragma unroll
        for (int r=0;r<4;++r){
          size_t off = (size_t)(mb + r)*N + n;
          float c = acc[rt][ct][r] + bv;
          if (MODE == 2) Cb[off] = f2bf(c);
          if (MODE == 3) Cf[off] += c;
        }
      }
    }
  }
}

// ---------------- fused GEMM + LayerNorm epilogue (TN = 256 = full D) ----------------
// C = A[M x K] @ BT[256 x K]^T + bias, then per row:
//   RES==1: t = C + bf2f(resid); t = LN(t; ga,ba); hn = h + t
//   RES==0: hn = h + C
//   h = hn; s2b = bf16(LN(hn; g2,b2))
template<int RES>
__global__ __launch_bounds__(256) void gemm_ln(
    const short* __restrict__ A, const short* __restrict__ BT,
    const float* __restrict__ bias, const short* __restrict__ residb,
    const float* __restrict__ ga, const float* __restrict__ ba,
    const float* __restrict__ g2, const float* __restrict__ b2,
    float* __restrict__ h, short* __restrict__ s2b, int K)
{
  __shared__ __align__(16) short As[64*32];    // 4 KB
  __shared__ __align__(16) short Bs[256*32];   // 16 KB
  const int t = threadIdx.x, wv = t>>6, lane = t&63;
  const int r16 = lane&15, quad = lane>>4;
  const int m0 = blockIdx.x*64;
  const short* Ab = A + (size_t)m0*K;
  const f32x4 z = {0.f,0.f,0.f,0.f};
  f32x4 acc[16];
  #pragma unroll
  for (int i=0;i<16;++i) acc[i] = z;

  for (int k0 = 0; k0 < K; k0 += 32){
    __syncthreads();
    g2l(Ab + (size_t)(t>>2)*K + k0 + (t&3)*8, As + t*8);
    #pragma unroll
    for (int j=0;j<4;++j){
      int c = j*256 + t;
      g2l(BT + (size_t)(c>>2)*K + k0 + (c&3)*8, Bs + c*8);
    }
    __syncthreads();
    bf16x8 af = *(const bf16x8*)(As + ((wv*16 + r16)*32 + quad*8));
    #pragma unroll
    for (int ct=0; ct<16; ++ct){
      bf16x8 bfr = *(const bf16x8*)(Bs + ((ct*16 + r16)*32 + quad*8));
      acc[ct] = __builtin_amdgcn_mfma_f32_16x16x32_bf16(af, bfr, acc[ct], 0,0,0);
    }
  }

  #pragma unroll
  for (int r=0;r<4;++r){
    const int R = m0 + wv*16 + quad*4 + r;
    float tv[16];
    #pragma unroll
    for (int ct=0;ct<16;++ct)
      tv[ct] = acc[ct][r] + bias[ct*16 + r16];
    if (RES){
      #pragma unroll
      for (int ct=0;ct<16;++ct)
        tv[ct] += bf2f(residb[(size_t)R*256 + ct*16 + r16]);
      float s=0.f, sq=0.f;
      #pragma unroll
      for (int ct=0;ct<16;++ct){ s += tv[ct]; sq += tv[ct]*tv[ct]; }
      #pragma unroll
      for (int m=1;m<16;m<<=1){ s += __shfl_xor(s,m,64); sq += __shfl_xor(sq,m,64); }
      float mean = s*(1.f/256.f);
      float var  = sq*(1.f/256.f) - mean*mean;
      float rstd = 1.f/sqrtf(var + LNEPS);
      #pragma unroll
      for (int ct=0;ct<16;++ct)
        tv[ct] = (tv[ct]-mean)*rstd*ga[ct*16+r16] + ba[ct*16+r16];
    }
    float hv[16];
    float s2=0.f, sq2=0.f;
    #pragma unroll
    for (int ct=0;ct<16;++ct){
      size_t off = (size_t)R*256 + ct*16 + r16;
      hv[ct] = h[off] + tv[ct];
      h[off] = hv[ct];
      s2 += hv[ct]; sq2 += hv[ct]*hv[ct];
    }
    #pragma unroll
    for (int m=1;m<16;m<<=1){ s2 += __shfl_xor(s2,m,64); sq2 += __shfl_xor(sq2,m,64); }
    float m2 = s2*(1.f/256.f);
    float v2 = sq2*(1.f/256.f) - m2*m2;
    float r2 = 1.f/sqrtf(v2 + LNEPS);
    #pragma unroll
    for (int ct=0;ct<16;++ct)
      s2b[(size_t)R*256 + ct*16 + r16] = f2bf((hv[ct]-m2)*r2*g2[ct*16+r16] + b2[ct*16+r16]);
  }
}

// ---------------- MFMA ProbSparse attention v4 ----------------
// Block = (bh, 16 q rows); XCD-pinned per head. QK scores stored TRANSPOSED:
// T[key][group^g(key)] as b64 (4 rows packed), g(key)=((key>>2)^(key>>4))&3
// (conflict-free writes & reads). Selection: 16 b64 reads give each wave
// 4 complete rows; single-pass 4-row-interleaved 16-step bit-descent on
// sortable keys (ballot+popcount); UNNORMALIZED bf16 weights written to
// PV layout [row][key ^ (row&7)<<3] in the same pass; 1/sum applied at
// output via the quad<->row identity (no LDS broadcast). LDS exactly 32 KB.
__global__ __launch_bounds__(256,4) void attn_mfma(
    const short* __restrict__ qkbf, const short* __restrict__ vT,
    short* __restrict__ ob)
{
  __shared__ __align__(16) short sc16[16*1024];   // 32768 B exactly
  const int t = threadIdx.x, wv = t>>6, lane = t&63;
  const int r16 = lane&15, quad = lane>>4;
  const int blk = blockIdx.x;
  const int bh = (blk & 7)*8 + ((blk>>3)&7);   // head's batch pinned to one XCD
  const int qt = blk >> 6;

  bf16x8 aq = *(const bf16x8*)(qkbf + ((size_t)bh*1024 + qt*16 + r16)*32 + quad*8);
  const short* kb = qkbf + (size_t)(64 + bh)*1024*32;

  // ---- QK: 16 key-tiles per wave; transposed b64 stores ----
  bf16x8 bk[16];
  #pragma unroll
  for (int tt=0; tt<16; ++tt)
    bk[tt] = *(const bf16x8*)(kb + (size_t)(wv*256 + tt*16 + r16)*32 + quad*8);
  #pragma unroll
  for (int tt=0; tt<16; ++tt){
    f32x4 c = {0.f,0.f,0.f,0.f};
    c = __builtin_amdgcn_mfma_f32_16x16x32_bf16(aq, bk[tt], c, 0, 0, 0);
    const int key = wv*256 + tt*16 + r16;
    const int g = ((key>>2) ^ (key>>4)) & 3;
    uint2 pk;
    pk.x = pk2bf(c[0], c[1]);     // rows quad*4+0, quad*4+1
    pk.y = pk2bf(c[2], c[3]);     // rows quad*4+2, quad*4+3
    *(uint2*)(sc16 + key*16 + ((quad ^ g)<<2)) = pk;
  }
  __syncthreads();

  // ---- read 4 complete rows (4wv..4wv+3), 1 key per lane per load ----
  uint2 rw[16];
  #pragma unroll
  for (int i=0;i<16;++i){
    int k = i*64 + lane;
    int g = ((k>>2) ^ (k>>4)) & 3;
    rw[i] = *(const uint2*)(sc16 + k*16 + ((wv ^ g)<<2));
  }
  __syncthreads();   // all T reads complete before weight overwrites

  int k0a[16], k1a[16], k2a[16], k3a[16];
  #pragma unroll
  for (int i=0;i<16;++i){
    k0a[i] = sortkey(rw[i].x & 0xFFFFu);
    k1a[i] = sortkey(rw[i].x >> 16);
    k2a[i] = sortkey(rw[i].y & 0xFFFFu);
    k3a[i] = sortkey(rw[i].y >> 16);
  }
  int mx0=k0a[0], mx1=k1a[0], mx2=k2a[0], mx3=k3a[0];
  #pragma unroll
  for (int i=1;i<16;++i){
    mx0 = (k0a[i]>mx0)?k0a[i]:mx0;
    mx1 = (k1a[i]>mx1)?k1a[i]:mx1;
    mx2 = (k2a[i]>mx2)?k2a[i]:mx2;
    mx3 = (k3a[i]>mx3)?k3a[i]:mx3;
  }
  #pragma unroll
  for (int o=32;o>0;o>>=1){
    int a;
    a = __shfl_xor(mx0,o,64); mx0 = (a>mx0)?a:mx0;
    a = __shfl_xor(mx1,o,64); mx1 = (a>mx1)?a:mx1;
    a = __shfl_xor(mx2,o,64); mx2 = (a>mx2)?a:mx2;
    a = __shfl_xor(mx3,o,64); mx3 = (a>mx3)?a:mx3;
  }
  // fixed 16-step bit-descent, 4 interleaved chains
  int lo0=0, lo1=0, lo2=0, lo3=0;
  #pragma unroll
  for (int bit=15; bit>=0; --bit){
    const int m0 = lo0 + (1<<bit), m1 = lo1 + (1<<bit);
    const int m2 = lo2 + (1<<bit), m3 = lo3 + (1<<bit);
    int c0=0, c1=0, c2=0, c3=0;
    #pragma unroll
    for (int i=0;i<16;++i){
      c0 += (int)__popcll(__ballot(k0a[i] >= m0));
      c1 += (int)__popcll(__ballot(k1a[i] >= m1));
      c2 += (int)__popcll(__ballot(k2a[i] >= m2));
      c3 += (int)__popcll(__ballot(k3a[i] >= m3));
    }
    if (c0 >= TOPK) lo0 = m0;
    if (c1 >= TOPK) lo1 = m1;
    if (c2 >= TOPK) lo2 = m2;
    if (c3 >= TOPK) lo3 = m3;
  }
  // ---- softmax (unnormalized) + weight write-back in one pass ----
  const float SC2 = 0.25500529485087056f;   // (1/sqrt(32)) * log2(e)
  const float nm0 = -kinvf(mx0)*SC2, nm1 = -kinvf(mx1)*SC2;
  const float nm2 = -kinvf(mx2)*SC2, nm3 = -kinvf(mx3)*SC2;
  const int r0 = wv*4;
  short* w0 = sc16 + (r0  )*1024;
  short* w1 = sc16 + (r0+1)*1024;
  short* w2 = sc16 + (r0+2)*1024;
  short* w3 = sc16 + (r0+3)*1024;
  const int s0 = ((r0  )&7)<<3, s1 = ((r0+1)&7)<<3;
  const int s2 = ((r0+2)&7)<<3, s3 = ((r0+3)&7)<<3;
  float sum0=0.f, sum1=0.f, sum2=0.f, sum3=0.f;
  #pragma unroll
  for (int i=0;i<16;++i){
    const int k = i*64 + lane;
    float e0 = (k0a[i] >= lo0) ? exp2f(fmaf(kinvf(k0a[i]), SC2, nm0)) : 0.f;
    float e1 = (k1a[i] >= lo1) ? exp2f(fmaf(kinvf(k1a[i]), SC2, nm1)) : 0.f;
    float e2 = (k2a[i] >= lo2) ? exp2f(fmaf(kinvf(k2a[i]), SC2, nm2)) : 0.f;
    float e3 = (k3a[i] >= lo3) ? exp2f(fmaf(kinvf(k3a[i]), SC2, nm3)) : 0.f;
    sum0 += e0; sum1 += e1; sum2 += e2; sum3 += e3;
    w0[k ^ s0] = f2bf(e0);
    w1[k ^ s1] = f2bf(e1);
    w2[k ^ s2] = f2bf(e2);
    w3[k ^ s3] = f2bf(e3);
  }
  sum0 = wsum(sum0); sum1 = wsum(sum1);
  sum2 = wsum(sum2); sum3 = wsum(sum3);
  const float sq_ = (quad==0)?sum0 : (quad==1)?sum1 : (quad==2)?sum2 : sum3;
  const float invq = 1.f/sq_;    // row wv*4+quad == output row t>>4
  __syncthreads();

  // ---- PV: wave wv covers keys wv*256..+255 ----
  const short* vb = vT + (size_t)bh*32*1024;
  bf16x8 bvv[16];
  #pragma unroll
  for (int tt=0; tt<8; ++tt){
    int k0 = wv*256 + tt*32;
    #pragma unroll
    for (int n=0;n<2;++n)
      bvv[tt*2+n] = *(const bf16x8*)(vb + (size_t)(n*16 + r16)*1024 + k0 + quad*8);
  }
  const int sA = (r16&7) << 3;         // s(row=r16)
  f32x4 oa0 = {0.f,0.f,0.f,0.f}, oa1 = {0.f,0.f,0.f,0.f};
  #pragma unroll
  for (int tt=0; tt<8; ++tt){
    int k0 = wv*256 + tt*32;
    bf16x8 af = *(const bf16x8*)(sc16 + r16*1024 + ((k0 + quad*8) ^ sA));
    oa0 = __builtin_amdgcn_mfma_f32_16x16x32_bf16(af, bvv[tt*2+0], oa0, 0, 0, 0);
    oa1 = __builtin_amdgcn_mfma_f32_16x16x32_bf16(af, bvv[tt*2+1], oa1, 0, 0, 0);
  }
  __syncthreads();
  float* po = (float*)sc16;            // 8 KB partials [wave][16q][32d]
  #pragma unroll
  for (int r=0;r<4;++r){
    po[wv*512 + (quad*4+r)*32 +      r16] = oa0[r];
    po[wv*512 + (quad*4+r)*32 + 16 + r16] = oa1[r];
  }
  __syncthreads();
  int e = t*2;
  float v0 = po[e]   + po[512+e]   + po[1024+e]   + po[1536+e];
  float v1 = po[e+1] + po[512+e+1] + po[1024+e+1] + po[1536+e+1];
  int q = e>>5, d = e&31;
  int b = bh>>3, hh = bh&7;
  size_t off = ((size_t)(b*1024 + qt*16 + q))*256 + hh*32 + d;
  *(unsigned*)(ob + off) = pk2bf(v0*invq, v1*invq);
}

// ---------------- Volatilite: f *= std_L(f), in place (bf16) ----------------
__global__ __launch_bounds__(512) void vol_scale(short* __restrict__ f)
{
  __shared__ float ps[8][64], pq[8][64], vs[64];
  int b = blockIdx.x >> 4, cb = blockIdx.x & 15;
  int cl = threadIdx.x & 63, sl = threadIdx.x >> 6;   // 8 waves x 128 L each
  int col = cb*64 + cl;
  short* fb = f + (size_t)b*L_*DFF + col;
  float s = 0.f, sq = 0.f;
  for (int l = sl*128; l < sl*128+128; ++l){
    float v = bf2f(fb[(size_t)l*DFF]);
    s += v; sq += v*v;
  }
  ps[sl][cl] = s; pq[sl][cl] = sq;
  __syncthreads();
  if (threadIdx.x < 64){
    float st=0.f, qt=0.f;
    #pragma unroll
    for (int i=0;i<8;++i){ st += ps[i][cl]; qt += pq[i][cl]; }
    float mean = st*(1.f/L_);
    float var  = qt*(1.f/L_) - mean*mean;
    vs[cl] = sqrtf(fmaxf(var, 0.f));
  }
  __syncthreads();
  float vv = vs[cl];
  for (int l = sl*128; l < sl*128+128; ++l){
    size_t o = (size_t)l*DFF;
    fb[o] = f2bf(bf2f(fb[o]) * vv);
  }
}

// ---------------- launch ----------------
extern "C" void kernel_launch(void* const* d_in, const int* in_sizes, int n_in,
                              void* d_out, int out_size, void* d_ws, size_t ws_size,
                              hipStream_t stream) {
  const float* x     = (const float*)d_in[0];
  const float* in_w  = (const float*)d_in[1];
  const float* in_b  = (const float*)d_in[2];
  const float* ln1_g = (const float*)d_in[3];
  const float* ln1_b = (const float*)d_in[4];
  const float* qkv_w = (const float*)d_in[5];
  const float* qkv_b = (const float*)d_in[6];
  const float* out_w = (const float*)d_in[7];
  const float* out_b = (const float*)d_in[8];
  const float* lna_g = (const float*)d_in[9];
  const float* lna_b = (const float*)d_in[10];
  const float* ln2_g = (const float*)d_in[11];
  const float* ln2_b = (const float*)d_in[12];
  const float* ff1_w = (const float*)d_in[13];
  const float* ff1_b = (const float*)d_in[14];
  const float* ff2_w = (const float*)d_in[15];
  const float* ff2_b = (const float*)d_in[16];
  const float* lnf_g = (const float*)d_in[17];
  const float* lnf_b = (const float*)d_in[18];
  float* out = (float*)d_out;

  // ws layout (~29.6 MB):
  //  h @0 8M | s2b @8M 4M | qkbf @12M 8M | vTb @20M 4M | ob_b @24M 4M
  //  f @12M 16M (aliases qkbf/vTb/ob_b — all dead at ff1 time)
  //  weights @28M: qkv 384K + out 128K + ff1 512K + ff2 512K
  char* ws = (char*)d_ws;
  float* h     = (float*)(ws);
  short* s2b   = (short*)(ws + (size_t)( 8<<20));
  short* qkbf  = (short*)(ws + (size_t)(12<<20));
  short* vTb   = (short*)(ws + (size_t)(20<<20));
  short* ob_b  = (short*)(ws + (size_t)(24<<20));
  short* f     = (short*)(ws + (size_t)(12<<20));
  short* qkvwT = (short*)(ws + (size_t)(28<<20));
  short* outwT = (short*)(ws + (size_t)(28<<20) + 393216);
  short* ff1wT = (short*)(ws + (size_t)(28<<20) + 393216 + 131072);
  short* ff2wT = (short*)(ws + (size_t)(28<<20) + 393216 + 131072 + 524288);

  embed_kernel<<<NR*64/256, 256, 0, stream>>>(x, in_w, in_b, h);
  wcvt<<< 768, 256, 0, stream>>>(qkv_w, qkvwT,  768, 8);
  wcvt<<< 256, 256, 0, stream>>>(out_w, outwT,  256, 8);
  wcvt<<<1024, 256, 0, stream>>>(ff1_w, ff1wT, 1024, 8);
  wcvt<<<1024, 256, 0, stream>>>(ff2_w, ff2wT,  256, 10);

  // s2b = bf16(LN1(h)) for layer 0
  ln_kernel<2><<<NR/4, 256, 0, stream>>>(h, ln1_g, ln1_b, nullptr, s2b);

  for (int layer = 0; layer < NLAYERS; ++layer){
    // qkv GEMM -> bf16 Q,K row-major + bf16 V^T
    {
      dim3 g(768/64, NR/128);
      mfma_gemm<0><<<g, 256, 0, stream>>>(s2b, qkvwT, qkv_b,
                                          nullptr, qkbf, vTb, 768, 256);
    }
    // ProbSparse attention -> ob bf16
    attn_mfma<<<64*64, 256, 0, stream>>>(qkbf, vTb, ob_b);
    // fused: t = ob@out_w+out_b+s2; h += LN_a(t); s2b = bf16(LN_2(h))
    gemm_ln<1><<<NR/64, 256, 0, stream>>>(ob_b, outwT, out_b, s2b,
                                          lna_g, lna_b, ln2_g, ln2_b,
                                          h, s2b, 256);
    // f = bf16(s2 @ ff1_w + ff1_b)
    {
      dim3 g(1024/64, NR/128);
      mfma_gemm<2><<<g, 256, 0, stream>>>(s2b, ff1wT, ff1_b,
                                          nullptr, f, nullptr, 1024, 256);
    }
    // f *= std_L(f) in place
    vol_scale<<<B_*16, 512, 0, stream>>>(f);
    // h += f @ ff2_w + ff2_b
    {
      dim3 g(256/64, NR/128);
      mfma_gemm<3><<<g, 256, 0, stream>>>(f, ff2wT, ff2_b,
                                          h, nullptr, nullptr, 256, 1024);
    }
    // s2b = bf16(LN1(h)) for next layer
    if (layer < NLAYERS-1)
      ln_kernel<2><<<NR/4, 256, 0, stream>>>(h, ln1_g, ln1_b, nullptr, s2b);
  }
  // out = LN_f(h)
  ln_kernel<0><<<NR/4, 256, 0, stream>>>(h, lnf_g, lnf_b, out, nullptr);
}

// Round 7
// 1272.620 us; speedup vs baseline: 1.2331x; 1.2331x over previous
//
#include <hip/hip_runtime.h>
#include <hip/hip_bf16.h>
#include <math.h>

#define D_MODEL 256
#define NH 8
#define DFF 1024
#define NLAYERS 6
#define B_ 8
#define L_ 1024
#define NR (B_*L_)          // 8192 rows
#define TOPK 256            // L/4
#define LNEPS 1e-5f

typedef __attribute__((ext_vector_type(8))) short bf16x8;
typedef __attribute__((ext_vector_type(4))) float f32x4;

// ---------------- helpers ----------------
__device__ __forceinline__ float wsum(float v){
  #pragma unroll
  for(int o=32;o>0;o>>=1) v += __shfl_xor(v,o,64);
  return v;
}
__device__ __forceinline__ short f2bf(float x){
  unsigned u = __float_as_uint(x);
  u += 0x7fffu + ((u>>16)&1u);   // RNE (finite inputs only)
  return (short)(u>>16);
}
__device__ __forceinline__ float bf2f(short s){
  return __uint_as_float(((unsigned)(unsigned short)s)<<16);
}
// packed 2x f32 -> 2x bf16 (v_cvt_pk_bf16_f32)
__device__ __forceinline__ unsigned pk2bf(float a, float b){
  __hip_bfloat162 h = __float22bfloat162_rn(make_float2(a,b));
  unsigned u; __builtin_memcpy(&u, &h, 4);
  return u;
}
// sortable 16-bit key -> float value (uniform use -> SALU)
__device__ __forceinline__ float kinvf(int k){
  unsigned u = (k & 0x8000) ? ((unsigned)k ^ 0x8000u) : ((unsigned)k ^ 0xFFFFu);
  return __uint_as_float(u << 16);
}
// async global->LDS, 16B per lane (dest = wave-uniform base + lane*16)
__device__ __forceinline__ void g2l(const short* g, short* l){
  __builtin_amdgcn_global_load_lds(
      (const __attribute__((address_space(1))) unsigned int*)g,
      (__attribute__((address_space(3))) unsigned int*)l,
      16, 0, 0);
}

// ---------------- embed: h = x@in_w + in_b + pe ----------------
__global__ __launch_bounds__(256) void embed_kernel(
    const float* __restrict__ x, const float* __restrict__ in_w,
    const float* __restrict__ in_b, float* __restrict__ h)
{
  int tid = blockIdx.x*256 + threadIdx.x;
  int n  = tid >> 6;
  int d0 = (tid & 63) << 2;
  int l  = n & (L_-1);
  float x0 = x[2*n], x1 = x[2*n+1];
  const float kf = -0.07195578415606394f;   // -ln(10000)/128
  float pe[4];
  #pragma unroll
  for(int ii=0; ii<2; ++ii){
    int i = (d0>>1) + ii;
    float dv  = expf((float)i * kf);
    float ang = (float)l * dv;
    pe[2*ii]   = sinf(ang);
    pe[2*ii+1] = cosf(ang);
  }
  float4 w0 = *(const float4*)(in_w + d0);
  float4 w1 = *(const float4*)(in_w + D_MODEL + d0);
  float4 bb = *(const float4*)(in_b + d0);
  float4 o;
  o.x = x0*w0.x + x1*w1.x + bb.x + pe[0];
  o.y = x0*w0.y + x1*w1.y + bb.y + pe[1];
  o.z = x0*w0.z + x1*w1.z + bb.z + pe[2];
  o.w = x0*w0.w + x1*w1.w + bb.w + pe[3];
  *(float4*)(h + (size_t)n*D_MODEL + d0) = o;
}

// ---------------- weight convert+transpose: WT[n][k] = bf16(W[k][n]) ----------------
__global__ __launch_bounds__(256) void wcvt(
    const float* __restrict__ W, short* __restrict__ WT, int N, int kshift)
{
  int idx = blockIdx.x*256 + threadIdx.x;
  int K = 1<<kshift;
  if (idx >= N*K) return;
  int n = idx >> kshift, k = idx & (K-1);
  WT[idx] = f2bf(W[(size_t)k*N + n]);
}

// ---------------- LayerNorm: wave per row ----------------
// OM: 0 = fp32 out, 2 = bf16 out only
template<int OM>
__global__ __launch_bounds__(256) void ln_kernel(
    const float* __restrict__ in, const float* __restrict__ g,
    const float* __restrict__ b, float* __restrict__ out,
    short* __restrict__ outb)
{
  int wave = threadIdx.x >> 6, lane = threadIdx.x & 63;
  int row = blockIdx.x*4 + wave;
  float4 v = ((const float4*)(in + (size_t)row*D_MODEL))[lane];
  float s  = v.x+v.y+v.z+v.w;
  float sq = v.x*v.x+v.y*v.y+v.z*v.z+v.w*v.w;
  s = wsum(s); sq = wsum(sq);
  float mean = s*(1.f/D_MODEL);
  float var  = sq*(1.f/D_MODEL) - mean*mean;
  float rstd = 1.f/sqrtf(var + LNEPS);
  float4 gv = ((const float4*)g)[lane];
  float4 bv = ((const float4*)b)[lane];
  float4 o;
  o.x = (v.x-mean)*rstd*gv.x + bv.x;
  o.y = (v.y-mean)*rstd*gv.y + bv.y;
  o.z = (v.z-mean)*rstd*gv.z + bv.z;
  o.w = (v.w-mean)*rstd*gv.w + bv.w;
  if (OM == 0){
    ((float4*)(out + (size_t)row*D_MODEL))[lane] = o;
  }
  if (OM == 2){
    uint2 pk; pk.x = pk2bf(o.x, o.y); pk.y = pk2bf(o.z, o.w);
    *(uint2*)(outb + (size_t)row*D_MODEL + lane*4) = pk;
  }
}

// ---------------- fused: h += LN_a(tb); s2b = bf16(LN_2(h)) ----------------
__global__ __launch_bounds__(256) void lnln_kernel(
    const float* __restrict__ tb,
    const float* __restrict__ ga, const float* __restrict__ ba,
    const float* __restrict__ g2, const float* __restrict__ b2,
    float* __restrict__ h, short* __restrict__ s2b)
{
  int wave = threadIdx.x >> 6, lane = threadIdx.x & 63;
  int row = blockIdx.x*4 + wave;
  float4 v = ((const float4*)(tb + (size_t)row*D_MODEL))[lane];
  float s  = v.x+v.y+v.z+v.w;
  float sq = v.x*v.x+v.y*v.y+v.z*v.z+v.w*v.w;
  s = wsum(s); sq = wsum(sq);
  float mean = s*(1.f/D_MODEL);
  float var  = sq*(1.f/D_MODEL) - mean*mean;
  float rstd = 1.f/sqrtf(var + LNEPS);
  float4 gv = ((const float4*)ga)[lane];
  float4 bv = ((const float4*)ba)[lane];
  float4* hp = (float4*)(h + (size_t)row*D_MODEL) + lane;
  float4 hv = *hp;
  float4 hn;
  hn.x = hv.x + (v.x-mean)*rstd*gv.x + bv.x;
  hn.y = hv.y + (v.y-mean)*rstd*gv.y + bv.y;
  hn.z = hv.z + (v.z-mean)*rstd*gv.z + bv.z;
  hn.w = hv.w + (v.w-mean)*rstd*gv.w + bv.w;
  *hp = hn;
  float s2  = hn.x+hn.y+hn.z+hn.w;
  float sq2 = hn.x*hn.x+hn.y*hn.y+hn.z*hn.z+hn.w*hn.w;
  s2 = wsum(s2); sq2 = wsum(sq2);
  float m2 = s2*(1.f/D_MODEL);
  float v2 = sq2*(1.f/D_MODEL) - m2*m2;
  float r2 = 1.f/sqrtf(v2 + LNEPS);
  float4 g2v = ((const float4*)g2)[lane];
  float4 b2v = ((const float4*)b2)[lane];
  uint2 pk;
  pk.x = pk2bf((hn.x-m2)*r2*g2v.x + b2v.x, (hn.y-m2)*r2*g2v.y + b2v.y);
  pk.y = pk2bf((hn.z-m2)*r2*g2v.z + b2v.z, (hn.w-m2)*r2*g2v.w + b2v.w);
  *(uint2*)(s2b + (size_t)row*D_MODEL + lane*4) = pk;
}

// ---------------- bf16 MFMA GEMM (round-4 measured-best): 128x64 tile, BK=32 ----------------
// MODE 0: qkv epilogue (Q/K row-major bf16 + V^T bf16)
// MODE 1: Cf = acc + bias + bf2f(residb)    (fp32 out)
// MODE 2: Cb = bf16(acc + bias)
// MODE 3: Cf += acc + bias                  (fp32 accumulate into h)
template<int MODE>
__global__ __launch_bounds__(256) void mfma_gemm(
    const short* __restrict__ A, const short* __restrict__ BT,
    const float* __restrict__ bias, const short* __restrict__ residb,
    float* __restrict__ Cf, short* __restrict__ Cb, short* __restrict__ Vt,
    int N, int K)
{
  __shared__ __align__(16) short As[128*32];   // 8 KB [m][k]
  __shared__ __align__(16) short Bs[64*32];    // 4 KB [n][k]
  const int t = threadIdx.x, wv = t>>6, lane = t&63;
  const int r16 = lane&15, quad = lane>>4;
  const int m0 = blockIdx.y*128, n0 = blockIdx.x*64;
  const int ia0 = wv*128 + lane, ia1 = ia0 + 64;
  const int ib  = wv*64 + lane;
  const short* Ab = A  + (size_t)m0*K;
  const short* Bb = BT + (size_t)n0*K;
  const f32x4 z = {0.f,0.f,0.f,0.f};
  f32x4 acc[2][4];
  #pragma unroll
  for (int i=0;i<2;++i)
    #pragma unroll
    for (int j=0;j<4;++j) acc[i][j] = z;

  for (int k0 = 0; k0 < K; k0 += 32){
    __syncthreads();
    g2l(Ab + (size_t)(ia0>>2)*K + k0 + (ia0&3)*8, As + ia0*8);
    g2l(Ab + (size_t)(ia1>>2)*K + k0 + (ia1&3)*8, As + ia1*8);
    g2l(Bb + (size_t)(ib>>2)*K  + k0 + (ib&3)*8,  Bs + ib*8);
    __syncthreads();
    bf16x8 af0 = *(const bf16x8*)(As + ((wv*32      + r16)*32 + quad*8));
    bf16x8 af1 = *(const bf16x8*)(As + ((wv*32 + 16 + r16)*32 + quad*8));
    bf16x8 bf[4];
    #pragma unroll
    for (int ct=0; ct<4; ++ct)
      bf[ct] = *(const bf16x8*)(Bs + ((ct*16 + r16)*32 + quad*8));
    #pragma unroll
    for (int ct=0; ct<4; ++ct){
      acc[0][ct] = __builtin_amdgcn_mfma_f32_16x16x32_bf16(af0, bf[ct], acc[0][ct], 0,0,0);
      acc[1][ct] = __builtin_amdgcn_mfma_f32_16x16x32_bf16(af1, bf[ct], acc[1][ct], 0,0,0);
    }
  }

  #pragma unroll
  for (int rt=0; rt<2; ++rt){
    const int mb = m0 + wv*32 + rt*16 + quad*4;
    #pragma unroll
    for (int ct=0; ct<4; ++ct){
      const int n = n0 + ct*16 + r16;
      const float bv = bias[n];
      if (MODE == 0){
        if (n < 512){                    // Q or K: qkbf[region*64+bh][l][d]
          int region = n>>8, hh = (n>>5)&7, d = n&31;
          #pragma unroll
          for (int r=0;r<4;++r){
            int l = mb + r;
            size_t base = (((size_t)(region*64 + (l>>10)*8 + hh))*1024 + (l&1023))*32 + d;
            Cb[base] = f2bf(acc[rt][ct][r] + bv);
          }
        } else {                         // V transposed: vT[bh][d][l]
          int dv = n - 512, hh = dv>>5, d = dv&31;
          int b = mb>>10, lloc = mb&1023;
          size_t base = (((size_t)(b*8 + hh))*32 + d)*1024 + lloc;
          uint2 pk;
          pk.x = pk2bf(acc[rt][ct][0] + bv, acc[rt][ct][1] + bv);
          pk.y = pk2bf(acc[rt][ct][2] + bv, acc[rt][ct][3] + bv);
          *(uint2*)(Vt + base) = pk;
        }
      } else {
        #pragma unroll
        for (int r=0;r<4;++r){
          size_t off = (size_t)(mb + r)*N + n;
          float c = acc[rt][ct][r] + bv;
          if (MODE == 1) Cf[off] = c + bf2f(residb[off]);
          if (MODE == 2) Cb[off] = f2bf(c);
          if (MODE == 3) Cf[off] += c;
        }
      }
    }
  }
}

// ---------------- MFMA ProbSparse attention v5 ----------------
// Block = (bh, 16 q rows); XCD-pinned per head. Scores bf16 in LDS
// [row][key ^ (row&7)<<3]. K/V fragments streamed in batches of 4 (low live
// regs; __launch_bounds__(256,5) -> LDS-limited 5 blocks/CU). Selection:
// 2-row-interleaved fixed 16-step bit-descent with FLOAT-domain compares
// (candidate thresholds walk the sortable-int grid, converted wave-uniformly
// -> SALU; no sortkey arrays). No max-subtraction (LN-bounded scores can't
// overflow exp2 in fp32). Unnormalized bf16 weights written back packed;
// 1/sum applied at output via the row==t>>4 identity.
__global__ __launch_bounds__(256,5) void attn_mfma(
    const short* __restrict__ qkbf, const short* __restrict__ vT,
    short* __restrict__ ob)
{
  __shared__ __align__(16) short sc16[16*1024];   // 32768 B exactly
  const int t = threadIdx.x, wv = t>>6, lane = t&63;
  const int r16 = lane&15, quad = lane>>4;
  const int blk = blockIdx.x;
  const int bh = (blk & 7)*8 + ((blk>>3)&7);   // head pinned to one XCD
  const int qt = blk >> 6;

  bf16x8 aq = *(const bf16x8*)(qkbf + ((size_t)bh*1024 + qt*16 + r16)*32 + quad*8);
  const short* kb = qkbf + (size_t)(64 + bh)*1024*32;
  short* p0 = sc16 + quad*4096;        // rows quad*4..quad*4+3

  // ---- QK: 16 key-tiles per wave, streamed in batches of 4 ----
  #pragma unroll
  for (int g=0; g<4; ++g){
    bf16x8 bkb[4];
    #pragma unroll
    for (int j=0;j<4;++j)
      bkb[j] = *(const bf16x8*)(kb + (size_t)(wv*256 + (g*4+j)*16 + r16)*32 + quad*8);
    #pragma unroll
    for (int j=0;j<4;++j){
      f32x4 c = {0.f,0.f,0.f,0.f};
      c = __builtin_amdgcn_mfma_f32_16x16x32_bf16(aq, bkb[j], c, 0, 0, 0);
      const int keyq = (wv*256 + (g*4+j)*16 + r16) ^ ((quad&1)<<5);
      unsigned u01 = pk2bf(c[0], c[1]);
      unsigned u23 = pk2bf(c[2], c[3]);
      p0[keyq]               = (short)u01;          // r=0
      p0[1024 + (keyq ^ 8)]  = (short)(u01>>16);    // r=1
      p0[2048 + (keyq ^ 16)] = (short)u23;          // r=2
      p0[3072 + (keyq ^ 24)] = (short)(u23>>16);    // r=3
    }
  }
  __syncthreads();

  // ---- selection + softmax: wave wv owns rows 4wv..4wv+3, two pairs ----
  const float SC2 = 0.25500529485087056f;   // (1/sqrt(32)) * log2(e)
  float iv0, iv1, iv2, iv3;                 // 1/sum for the 4 rows
  #pragma unroll
  for (int rp=0; rp<2; ++rp){
    const int ra = wv*4 + rp*2;
    const int sa = (ra&7)<<3;                 // ra even
    short* pa = sc16 + ra*1024 + ((2*lane) ^ sa);
    short* pb = sc16 + (ra+1)*1024 + (((2*lane) ^ sa) ^ 8);
    float fa[16], fb[16];
    #pragma unroll
    for (int i=0;i<8;++i){
      unsigned wa = *(const unsigned*)(pa + i*128);
      unsigned wb = *(const unsigned*)(pb + i*128);
      fa[2*i]   = __uint_as_float(wa << 16);
      fa[2*i+1] = __uint_as_float(wa & 0xFFFF0000u);
      fb[2*i]   = __uint_as_float(wb << 16);
      fb[2*i+1] = __uint_as_float(wb & 0xFFFF0000u);
    }
    // fixed 16-step bit-descent over sortable-int candidates, float compares
    int loA = 0, loB = 0;
    #pragma unroll
    for (int bit = 15; bit >= 0; --bit){
      const int mA = loA | (1<<bit);
      const int mB = loB | (1<<bit);
      const float tA = kinvf(mA);   // wave-uniform -> SALU
      const float tB = kinvf(mB);
      int cA = 0, cB = 0;
      #pragma unroll
      for (int i=0;i<16;++i){
        cA += (int)__popcll(__ballot(fa[i] >= tA));
        cB += (int)__popcll(__ballot(fb[i] >= tB));
      }
      if (cA >= TOPK) loA = mA;
      if (cB >= TOPK) loB = mB;
    }
    const float thrA = kinvf(loA), thrB = kinvf(loB);
    float suma = 0.f, sumb = 0.f;
    unsigned pka[8], pkb[8];
    #pragma unroll
    for (int i=0;i<8;++i){
      float ea0 = (fa[2*i]   >= thrA) ? exp2f(fa[2*i]  *SC2) : 0.f;
      float ea1 = (fa[2*i+1] >= thrA) ? exp2f(fa[2*i+1]*SC2) : 0.f;
      float eb0 = (fb[2*i]   >= thrB) ? exp2f(fb[2*i]  *SC2) : 0.f;
      float eb1 = (fb[2*i+1] >= thrB) ? exp2f(fb[2*i+1]*SC2) : 0.f;
      suma += ea0 + ea1; sumb += eb0 + eb1;
      pka[i] = pk2bf(ea0, ea1);
      pkb[i] = pk2bf(eb0, eb1);
    }
    suma = wsum(suma); sumb = wsum(sumb);
    if (rp == 0){ iv0 = 1.f/suma; iv1 = 1.f/sumb; }
    else        { iv2 = 1.f/suma; iv3 = 1.f/sumb; }
    #pragma unroll
    for (int i=0;i<8;++i){
      *(unsigned*)(pa + i*128) = pka[i];
      *(unsigned*)(pb + i*128) = pkb[i];
    }
  }
  const float invq = (quad==0)?iv0 : (quad==1)?iv1 : (quad==2)?iv2 : iv3;
  __syncthreads();

  // ---- PV: wave wv covers keys wv*256..+255, V streamed in batches ----
  const short* vb = vT + (size_t)bh*32*1024;
  const int sA = (r16&7) << 3;         // s(row=r16)
  f32x4 oa0 = {0.f,0.f,0.f,0.f}, oa1 = {0.f,0.f,0.f,0.f};
  #pragma unroll
  for (int g=0; g<4; ++g){
    bf16x8 bvb[4];
    #pragma unroll
    for (int j=0;j<2;++j){
      int k0 = wv*256 + (g*2+j)*32;
      bvb[j*2+0] = *(const bf16x8*)(vb + (size_t)(     r16)*1024 + k0 + quad*8);
      bvb[j*2+1] = *(const bf16x8*)(vb + (size_t)(16 + r16)*1024 + k0 + quad*8);
    }
    #pragma unroll
    for (int j=0;j<2;++j){
      int k0 = wv*256 + (g*2+j)*32;
      bf16x8 af = *(const bf16x8*)(sc16 + r16*1024 + ((k0 + quad*8) ^ sA));
      oa0 = __builtin_amdgcn_mfma_f32_16x16x32_bf16(af, bvb[j*2+0], oa0, 0, 0, 0);
      oa1 = __builtin_amdgcn_mfma_f32_16x16x32_bf16(af, bvb[j*2+1], oa1, 0, 0, 0);
    }
  }
  __syncthreads();
  float* po = (float*)sc16;            // 8 KB partials [wave][16q][32d]
  #pragma unroll
  for (int r=0;r<4;++r){
    po[wv*512 + (quad*4+r)*32 +      r16] = oa0[r];
    po[wv*512 + (quad*4+r)*32 + 16 + r16] = oa1[r];
  }
  __syncthreads();
  int e = t*2;
  float v0 = po[e]   + po[512+e]   + po[1024+e]   + po[1536+e];
  float v1 = po[e+1] + po[512+e+1] + po[1024+e+1] + po[1536+e+1];
  int q = e>>5, d = e&31;
  int b = bh>>3, hh = bh&7;
  size_t off = ((size_t)(b*1024 + qt*16 + q))*256 + hh*32 + d;
  *(unsigned*)(ob + off) = pk2bf(v0*invq, v1*invq);
}

// ---------------- Volatilite: f *= std_L(f), in place (bf16) ----------------
__global__ __launch_bounds__(512) void vol_scale(short* __restrict__ f)
{
  __shared__ float ps[8][64], pq[8][64], vs[64];
  int b = blockIdx.x >> 4, cb = blockIdx.x & 15;
  int cl = threadIdx.x & 63, sl = threadIdx.x >> 6;   // 8 waves x 128 L each
  int col = cb*64 + cl;
  short* fb = f + (size_t)b*L_*DFF + col;
  float s = 0.f, sq = 0.f;
  for (int l = sl*128; l < sl*128+128; ++l){
    float v = bf2f(fb[(size_t)l*DFF]);
    s += v; sq += v*v;
  }
  ps[sl][cl] = s; pq[sl][cl] = sq;
  __syncthreads();
  if (threadIdx.x < 64){
    float st=0.f, qt=0.f;
    #pragma unroll
    for (int i=0;i<8;++i){ st += ps[i][cl]; qt += pq[i][cl]; }
    float mean = st*(1.f/L_);
    float var  = qt*(1.f/L_) - mean*mean;
    vs[cl] = sqrtf(fmaxf(var, 0.f));
  }
  __syncthreads();
  float vv = vs[cl];
  for (int l = sl*128; l < sl*128+128; ++l){
    size_t o = (size_t)l*DFF;
    fb[o] = f2bf(bf2f(fb[o]) * vv);
  }
}

// ---------------- launch ----------------
extern "C" void kernel_launch(void* const* d_in, const int* in_sizes, int n_in,
                              void* d_out, int out_size, void* d_ws, size_t ws_size,
                              hipStream_t stream) {
  const float* x     = (const float*)d_in[0];
  const float* in_w  = (const float*)d_in[1];
  const float* in_b  = (const float*)d_in[2];
  const float* ln1_g = (const float*)d_in[3];
  const float* ln1_b = (const float*)d_in[4];
  const float* qkv_w = (const float*)d_in[5];
  const float* qkv_b = (const float*)d_in[6];
  const float* out_w = (const float*)d_in[7];
  const float* out_b = (const float*)d_in[8];
  const float* lna_g = (const float*)d_in[9];
  const float* lna_b = (const float*)d_in[10];
  const float* ln2_g = (const float*)d_in[11];
  const float* ln2_b = (const float*)d_in[12];
  const float* ff1_w = (const float*)d_in[13];
  const float* ff1_b = (const float*)d_in[14];
  const float* ff2_w = (const float*)d_in[15];
  const float* ff2_b = (const float*)d_in[16];
  const float* lnf_g = (const float*)d_in[17];
  const float* lnf_b = (const float*)d_in[18];
  float* out = (float*)d_out;

  // ws layout (round-4, ~37.6 MB):
  //  h @0 8M | s2b @8M 4M | qkbf @12M 8M | vTb @20M 4M | ob_b @24M 4M
  //  f @12M 16M (aliases qkbf/vTb/ob_b — dead at ff1 time) | tb @28M 8M
  //  weights @36M: qkv 384K + out 128K + ff1 512K + ff2 512K
  char* ws = (char*)d_ws;
  float* h     = (float*)(ws);
  short* s2b   = (short*)(ws + (size_t)( 8<<20));
  short* qkbf  = (short*)(ws + (size_t)(12<<20));
  short* vTb   = (short*)(ws + (size_t)(20<<20));
  short* ob_b  = (short*)(ws + (size_t)(24<<20));
  short* f     = (short*)(ws + (size_t)(12<<20));
  float* tb    = (float*)(ws + (size_t)(28<<20));
  short* qkvwT = (short*)(ws + (size_t)(36<<20));
  short* outwT = (short*)(ws + (size_t)(36<<20) + 393216);
  short* ff1wT = (short*)(ws + (size_t)(36<<20) + 393216 + 131072);
  short* ff2wT = (short*)(ws + (size_t)(36<<20) + 393216 + 131072 + 524288);

  embed_kernel<<<NR*64/256, 256, 0, stream>>>(x, in_w, in_b, h);
  wcvt<<< 768, 256, 0, stream>>>(qkv_w, qkvwT,  768, 8);
  wcvt<<< 256, 256, 0, stream>>>(out_w, outwT,  256, 8);
  wcvt<<<1024, 256, 0, stream>>>(ff1_w, ff1wT, 1024, 8);
  wcvt<<<1024, 256, 0, stream>>>(ff2_w, ff2wT,  256, 10);

  for (int layer = 0; layer < NLAYERS; ++layer){
    // s2b = bf16(LN1(h))
    ln_kernel<2><<<NR/4, 256, 0, stream>>>(h, ln1_g, ln1_b, nullptr, s2b);
    // qkv GEMM -> bf16 Q,K row-major + bf16 V^T
    {
      dim3 g(768/64, NR/128);
      mfma_gemm<0><<<g, 256, 0, stream>>>(s2b, qkvwT, qkv_b, nullptr,
                                          nullptr, qkbf, vTb, 768, 256);
    }
    // ProbSparse attention -> ob bf16
    attn_mfma<<<64*64, 256, 0, stream>>>(qkbf, vTb, ob_b);
    // tb = ob @ out_w + out_b + s2 (fp32)
    {
      dim3 g(256/64, NR/128);
      mfma_gemm<1><<<g, 256, 0, stream>>>(ob_b, outwT, out_b, s2b,
                                          tb, nullptr, nullptr, 256, 256);
    }
    // h += LN_a(tb); s2b = bf16(LN_2(h))
    lnln_kernel<<<NR/4, 256, 0, stream>>>(tb, lna_g, lna_b, ln2_g, ln2_b, h, s2b);
    // f = bf16(s2 @ ff1_w + ff1_b)
    {
      dim3 g(1024/64, NR/128);
      mfma_gemm<2><<<g, 256, 0, stream>>>(s2b, ff1wT, ff1_b, nullptr,
                                          nullptr, f, nullptr, 1024, 256);
    }
    // f *= std_L(f) in place
    vol_scale<<<B_*16, 512, 0, stream>>>(f);
    // h += f @ ff2_w + ff2_b
    {
      dim3 g(256/64, NR/128);
      mfma_gemm<3><<<g, 256, 0, stream>>>(f, ff2wT, ff2_b, nullptr,
                                          h, nullptr, nullptr, 256, 1024);
    }
  }
  // out = LN_f(h)
  ln_kernel<0><<<NR/4, 256, 0, stream>>>(h, lnf_g, lnf_b, out, nullptr);
}

// Round 8
// 1180.465 us; speedup vs baseline: 1.3294x; 1.0781x over previous
//
#include <hip/hip_runtime.h>
#include <hip/hip_bf16.h>
#include <math.h>

#define D_MODEL 256
#define NH 8
#define DFF 1024
#define NLAYERS 6
#define B_ 8
#define L_ 1024
#define NR (B_*L_)          // 8192 rows
#define TOPK 256            // L/4
#define LNEPS 1e-5f

typedef __attribute__((ext_vector_type(8))) short bf16x8;
typedef __attribute__((ext_vector_type(4))) float f32x4;

// ---------------- helpers ----------------
__device__ __forceinline__ float wsum(float v){
  #pragma unroll
  for(int o=32;o>0;o>>=1) v += __shfl_xor(v,o,64);
  return v;
}
__device__ __forceinline__ short f2bf(float x){
  unsigned u = __float_as_uint(x);
  u += 0x7fffu + ((u>>16)&1u);   // RNE (finite inputs only)
  return (short)(u>>16);
}
__device__ __forceinline__ float bf2f(short s){
  return __uint_as_float(((unsigned)(unsigned short)s)<<16);
}
// packed 2x f32 -> 2x bf16 (v_cvt_pk_bf16_f32)
__device__ __forceinline__ unsigned pk2bf(float a, float b){
  __hip_bfloat162 h = __float22bfloat162_rn(make_float2(a,b));
  unsigned u; __builtin_memcpy(&u, &h, 4);
  return u;
}
// sortable 16-bit key -> float value (uniform use -> SALU)
__device__ __forceinline__ float kinvf(int k){
  unsigned u = (k & 0x8000) ? ((unsigned)k ^ 0x8000u) : ((unsigned)k ^ 0xFFFFu);
  return __uint_as_float(u << 16);
}
// async global->LDS, 16B per lane (dest = wave-uniform base + lane*16)
__device__ __forceinline__ void g2l(const short* g, short* l){
  __builtin_amdgcn_global_load_lds(
      (const __attribute__((address_space(1))) unsigned int*)g,
      (__attribute__((address_space(3))) unsigned int*)l,
      16, 0, 0);
}

// ---------------- embed: h = x@in_w + in_b + pe ----------------
__global__ __launch_bounds__(256) void embed_kernel(
    const float* __restrict__ x, const float* __restrict__ in_w,
    const float* __restrict__ in_b, float* __restrict__ h)
{
  int tid = blockIdx.x*256 + threadIdx.x;
  int n  = tid >> 6;
  int d0 = (tid & 63) << 2;
  int l  = n & (L_-1);
  float x0 = x[2*n], x1 = x[2*n+1];
  const float kf = -0.07195578415606394f;   // -ln(10000)/128
  float pe[4];
  #pragma unroll
  for(int ii=0; ii<2; ++ii){
    int i = (d0>>1) + ii;
    float dv  = expf((float)i * kf);
    float ang = (float)l * dv;
    pe[2*ii]   = sinf(ang);
    pe[2*ii+1] = cosf(ang);
  }
  float4 w0 = *(const float4*)(in_w + d0);
  float4 w1 = *(const float4*)(in_w + D_MODEL + d0);
  float4 bb = *(const float4*)(in_b + d0);
  float4 o;
  o.x = x0*w0.x + x1*w1.x + bb.x + pe[0];
  o.y = x0*w0.y + x1*w1.y + bb.y + pe[1];
  o.z = x0*w0.z + x1*w1.z + bb.z + pe[2];
  o.w = x0*w0.w + x1*w1.w + bb.w + pe[3];
  *(float4*)(h + (size_t)n*D_MODEL + d0) = o;
}

// ---------------- weight convert+transpose: WT[n][k] = bf16(W[k][n]) ----------------
__global__ __launch_bounds__(256) void wcvt(
    const float* __restrict__ W, short* __restrict__ WT, int N, int kshift)
{
  int idx = blockIdx.x*256 + threadIdx.x;
  int K = 1<<kshift;
  if (idx >= N*K) return;
  int n = idx >> kshift, k = idx & (K-1);
  WT[idx] = f2bf(W[(size_t)k*N + n]);
}

// ---------------- LayerNorm: wave per row ----------------
// OM: 0 = fp32 out, 2 = bf16 out only
template<int OM>
__global__ __launch_bounds__(256) void ln_kernel(
    const float* __restrict__ in, const float* __restrict__ g,
    const float* __restrict__ b, float* __restrict__ out,
    short* __restrict__ outb)
{
  int wave = threadIdx.x >> 6, lane = threadIdx.x & 63;
  int row = blockIdx.x*4 + wave;
  float4 v = ((const float4*)(in + (size_t)row*D_MODEL))[lane];
  float s  = v.x+v.y+v.z+v.w;
  float sq = v.x*v.x+v.y*v.y+v.z*v.z+v.w*v.w;
  s = wsum(s); sq = wsum(sq);
  float mean = s*(1.f/D_MODEL);
  float var  = sq*(1.f/D_MODEL) - mean*mean;
  float rstd = 1.f/sqrtf(var + LNEPS);
  float4 gv = ((const float4*)g)[lane];
  float4 bv = ((const float4*)b)[lane];
  float4 o;
  o.x = (v.x-mean)*rstd*gv.x + bv.x;
  o.y = (v.y-mean)*rstd*gv.y + bv.y;
  o.z = (v.z-mean)*rstd*gv.z + bv.z;
  o.w = (v.w-mean)*rstd*gv.w + bv.w;
  if (OM == 0){
    ((float4*)(out + (size_t)row*D_MODEL))[lane] = o;
  }
  if (OM == 2){
    uint2 pk; pk.x = pk2bf(o.x, o.y); pk.y = pk2bf(o.z, o.w);
    *(uint2*)(outb + (size_t)row*D_MODEL + lane*4) = pk;
  }
}

// ---------------- fused: h += LN_a(tb); s2b = bf16(LN_2(h)) ----------------
__global__ __launch_bounds__(256) void lnln_kernel(
    const float* __restrict__ tb,
    const float* __restrict__ ga, const float* __restrict__ ba,
    const float* __restrict__ g2, const float* __restrict__ b2,
    float* __restrict__ h, short* __restrict__ s2b)
{
  int wave = threadIdx.x >> 6, lane = threadIdx.x & 63;
  int row = blockIdx.x*4 + wave;
  float4 v = ((const float4*)(tb + (size_t)row*D_MODEL))[lane];
  float s  = v.x+v.y+v.z+v.w;
  float sq = v.x*v.x+v.y*v.y+v.z*v.z+v.w*v.w;
  s = wsum(s); sq = wsum(sq);
  float mean = s*(1.f/D_MODEL);
  float var  = sq*(1.f/D_MODEL) - mean*mean;
  float rstd = 1.f/sqrtf(var + LNEPS);
  float4 gv = ((const float4*)ga)[lane];
  float4 bv = ((const float4*)ba)[lane];
  float4* hp = (float4*)(h + (size_t)row*D_MODEL) + lane;
  float4 hv = *hp;
  float4 hn;
  hn.x = hv.x + (v.x-mean)*rstd*gv.x + bv.x;
  hn.y = hv.y + (v.y-mean)*rstd*gv.y + bv.y;
  hn.z = hv.z + (v.z-mean)*rstd*gv.z + bv.z;
  hn.w = hv.w + (v.w-mean)*rstd*gv.w + bv.w;
  *hp = hn;
  float s2  = hn.x+hn.y+hn.z+hn.w;
  float sq2 = hn.x*hn.x+hn.y*hn.y+hn.z*hn.z+hn.w*hn.w;
  s2 = wsum(s2); sq2 = wsum(sq2);
  float m2 = s2*(1.f/D_MODEL);
  float v2 = sq2*(1.f/D_MODEL) - m2*m2;
  float r2 = 1.f/sqrtf(v2 + LNEPS);
  float4 g2v = ((const float4*)g2)[lane];
  float4 b2v = ((const float4*)b2)[lane];
  uint2 pk;
  pk.x = pk2bf((hn.x-m2)*r2*g2v.x + b2v.x, (hn.y-m2)*r2*g2v.y + b2v.y);
  pk.y = pk2bf((hn.z-m2)*r2*g2v.z + b2v.z, (hn.w-m2)*r2*g2v.w + b2v.w);
  *(uint2*)(s2b + (size_t)row*D_MODEL + lane*4) = pk;
}

// ---------------- bf16 MFMA GEMM: 128x64 tile, BK=32 (measured-best) ----------------
// MODE 0: qkv epilogue (Q/K row-major bf16 + V^T bf16)
// MODE 1: Cf = acc + bias + bf2f(residb)    (fp32 out)
// MODE 2: Cb = bf16(acc + bias)
// MODE 3: Cf += acc + bias                  (fp32 accumulate into h)
template<int MODE>
__global__ __launch_bounds__(256) void mfma_gemm(
    const short* __restrict__ A, const short* __restrict__ BT,
    const float* __restrict__ bias, const short* __restrict__ residb,
    float* __restrict__ Cf, short* __restrict__ Cb, short* __restrict__ Vt,
    int N, int K)
{
  __shared__ __align__(16) short As[128*32];   // 8 KB [m][k]
  __shared__ __align__(16) short Bs[64*32];    // 4 KB [n][k]
  const int t = threadIdx.x, wv = t>>6, lane = t&63;
  const int r16 = lane&15, quad = lane>>4;
  const int m0 = blockIdx.y*128, n0 = blockIdx.x*64;
  const int ia0 = wv*128 + lane, ia1 = ia0 + 64;
  const int ib  = wv*64 + lane;
  const short* Ab = A  + (size_t)m0*K;
  const short* Bb = BT + (size_t)n0*K;
  const f32x4 z = {0.f,0.f,0.f,0.f};
  f32x4 acc[2][4];
  #pragma unroll
  for (int i=0;i<2;++i)
    #pragma unroll
    for (int j=0;j<4;++j) acc[i][j] = z;

  for (int k0 = 0; k0 < K; k0 += 32){
    __syncthreads();
    g2l(Ab + (size_t)(ia0>>2)*K + k0 + (ia0&3)*8, As + ia0*8);
    g2l(Ab + (size_t)(ia1>>2)*K + k0 + (ia1&3)*8, As + ia1*8);
    g2l(Bb + (size_t)(ib>>2)*K  + k0 + (ib&3)*8,  Bs + ib*8);
    __syncthreads();
    bf16x8 af0 = *(const bf16x8*)(As + ((wv*32      + r16)*32 + quad*8));
    bf16x8 af1 = *(const bf16x8*)(As + ((wv*32 + 16 + r16)*32 + quad*8));
    bf16x8 bf[4];
    #pragma unroll
    for (int ct=0; ct<4; ++ct)
      bf[ct] = *(const bf16x8*)(Bs + ((ct*16 + r16)*32 + quad*8));
    #pragma unroll
    for (int ct=0; ct<4; ++ct){
      acc[0][ct] = __builtin_amdgcn_mfma_f32_16x16x32_bf16(af0, bf[ct], acc[0][ct], 0,0,0);
      acc[1][ct] = __builtin_amdgcn_mfma_f32_16x16x32_bf16(af1, bf[ct], acc[1][ct], 0,0,0);
    }
  }

  #pragma unroll
  for (int rt=0; rt<2; ++rt){
    const int mb = m0 + wv*32 + rt*16 + quad*4;
    #pragma unroll
    for (int ct=0; ct<4; ++ct){
      const int n = n0 + ct*16 + r16;
      const float bv = bias[n];
      if (MODE == 0){
        if (n < 512){                    // Q or K: qkbf[region*64+bh][l][d]
          int region = n>>8, hh = (n>>5)&7, d = n&31;
          #pragma unroll
          for (int r=0;r<4;++r){
            int l = mb + r;
            size_t base = (((size_t)(region*64 + (l>>10)*8 + hh))*1024 + (l&1023))*32 + d;
            Cb[base] = f2bf(acc[rt][ct][r] + bv);
          }
        } else {                         // V transposed: vT[bh][d][l]
          int dv = n - 512, hh = dv>>5, d = dv&31;
          int b = mb>>10, lloc = mb&1023;
          size_t base = (((size_t)(b*8 + hh))*32 + d)*1024 + lloc;
          uint2 pk;
          pk.x = pk2bf(acc[rt][ct][0] + bv, acc[rt][ct][1] + bv);
          pk.y = pk2bf(acc[rt][ct][2] + bv, acc[rt][ct][3] + bv);
          *(uint2*)(Vt + base) = pk;
        }
      } else {
        #pragma unroll
        for (int r=0;r<4;++r){
          size_t off = (size_t)(mb + r)*N + n;
          float c = acc[rt][ct][r] + bv;
          if (MODE == 1) Cf[off] = c + bf2f(residb[off]);
          if (MODE == 2) Cb[off] = f2bf(c);
          if (MODE == 3) Cf[off] += c;
        }
      }
    }
  }
}

// ---------------- MFMA ProbSparse attention v6: 8 waves / block ----------------
// Block = (bh, 16 q rows), 512 threads. Each wave: 8 QK key-tiles, 2 selection
// rows (single pass), 4 PV tiles -> half the serial work of v5. O-partials in
// a separate 16 KB region; LDS 48 KB -> 3 blocks x 8 waves = 24 waves/CU (75%).
// Scores bf16 [row][key ^ (row&7)<<3]; float-domain fixed 16-step bit-descent
// (thresholds walk the sortable grid wave-uniformly -> SALU); normalized bf16
// weights written back; output = plain partial sum.
__global__ __launch_bounds__(512,6) void attn_mfma(
    const short* __restrict__ qkbf, const short* __restrict__ vT,
    short* __restrict__ ob)
{
  __shared__ __align__(16) short sc16[16*1024];   // 32 KB scores/weights
  __shared__ __align__(16) float po[8*512];       // 16 KB O partials
  const int t = threadIdx.x, wv = t>>6, lane = t&63;
  const int r16 = lane&15, quad = lane>>4;
  const int blk = blockIdx.x;
  const int bh = (blk & 7)*8 + ((blk>>3)&7);   // head pinned to one XCD
  const int qt = blk >> 6;

  bf16x8 aq = *(const bf16x8*)(qkbf + ((size_t)bh*1024 + qt*16 + r16)*32 + quad*8);
  const short* kb = qkbf + (size_t)(64 + bh)*1024*32;
  short* p0 = sc16 + quad*4096;        // rows quad*4..quad*4+3

  // ---- QK: 8 key-tiles per wave (keys wv*128..+127) ----
  #pragma unroll
  for (int g=0; g<2; ++g){
    bf16x8 bkb[4];
    #pragma unroll
    for (int j=0;j<4;++j)
      bkb[j] = *(const bf16x8*)(kb + (size_t)(wv*128 + (g*4+j)*16 + r16)*32 + quad*8);
    #pragma unroll
    for (int j=0;j<4;++j){
      f32x4 c = {0.f,0.f,0.f,0.f};
      c = __builtin_amdgcn_mfma_f32_16x16x32_bf16(aq, bkb[j], c, 0, 0, 0);
      const int keyq = (wv*128 + (g*4+j)*16 + r16) ^ ((quad&1)<<5);
      unsigned u01 = pk2bf(c[0], c[1]);
      unsigned u23 = pk2bf(c[2], c[3]);
      p0[keyq]               = (short)u01;          // r=0
      p0[1024 + (keyq ^ 8)]  = (short)(u01>>16);    // r=1
      p0[2048 + (keyq ^ 16)] = (short)u23;          // r=2
      p0[3072 + (keyq ^ 24)] = (short)(u23>>16);    // r=3
    }
  }
  __syncthreads();

  // ---- selection + softmax: wave wv owns rows 2wv, 2wv+1 (one pass) ----
  const float SC2 = 0.25500529485087056f;   // (1/sqrt(32)) * log2(e)
  {
    const int ra = wv*2;
    const int sa = (ra&7)<<3;                 // ra even
    short* pa = sc16 + ra*1024 + ((2*lane) ^ sa);
    short* pb = sc16 + (ra+1)*1024 + (((2*lane) ^ sa) ^ 8);
    float fa[16], fb[16];
    #pragma unroll
    for (int i=0;i<8;++i){
      unsigned wa = *(const unsigned*)(pa + i*128);
      unsigned wb = *(const unsigned*)(pb + i*128);
      fa[2*i]   = __uint_as_float(wa << 16);
      fa[2*i+1] = __uint_as_float(wa & 0xFFFF0000u);
      fb[2*i]   = __uint_as_float(wb << 16);
      fb[2*i+1] = __uint_as_float(wb & 0xFFFF0000u);
    }
    // fixed 16-step bit-descent over sortable-int candidates, float compares
    int loA = 0, loB = 0;
    #pragma unroll
    for (int bit = 15; bit >= 0; --bit){
      const int mA = loA | (1<<bit);
      const int mB = loB | (1<<bit);
      const float tA = kinvf(mA);   // wave-uniform -> SALU
      const float tB = kinvf(mB);
      int cA = 0, cB = 0;
      #pragma unroll
      for (int i=0;i<16;++i){
        cA += (int)__popcll(__ballot(fa[i] >= tA));
        cB += (int)__popcll(__ballot(fb[i] >= tB));
      }
      if (cA >= TOPK) loA = mA;
      if (cB >= TOPK) loB = mB;
    }
    const float thrA = kinvf(loA), thrB = kinvf(loB);
    float ea[16], eb[16];
    float suma = 0.f, sumb = 0.f;
    #pragma unroll
    for (int i=0;i<16;++i){
      ea[i] = (fa[i] >= thrA) ? exp2f(fa[i]*SC2) : 0.f;
      eb[i] = (fb[i] >= thrB) ? exp2f(fb[i]*SC2) : 0.f;
      suma += ea[i]; sumb += eb[i];
    }
    suma = wsum(suma); sumb = wsum(sumb);
    const float inva = 1.f/suma, invb = 1.f/sumb;
    #pragma unroll
    for (int i=0;i<8;++i){
      *(unsigned*)(pa + i*128) = pk2bf(ea[2*i]*inva, ea[2*i+1]*inva);
      *(unsigned*)(pb + i*128) = pk2bf(eb[2*i]*invb, eb[2*i+1]*invb);
    }
  }
  __syncthreads();

  // ---- PV: wave wv covers keys wv*128..+127 (4 tiles of 32) ----
  const short* vb = vT + (size_t)bh*32*1024;
  const int sA = (r16&7) << 3;         // s(row=r16)
  f32x4 oa0 = {0.f,0.f,0.f,0.f}, oa1 = {0.f,0.f,0.f,0.f};
  #pragma unroll
  for (int j=0;j<4;++j){
    int k0 = wv*128 + j*32;
    bf16x8 b0 = *(const bf16x8*)(vb + (size_t)(     r16)*1024 + k0 + quad*8);
    bf16x8 b1 = *(const bf16x8*)(vb + (size_t)(16 + r16)*1024 + k0 + quad*8);
    bf16x8 af = *(const bf16x8*)(sc16 + r16*1024 + ((k0 + quad*8) ^ sA));
    oa0 = __builtin_amdgcn_mfma_f32_16x16x32_bf16(af, b0, oa0, 0, 0, 0);
    oa1 = __builtin_amdgcn_mfma_f32_16x16x32_bf16(af, b1, oa1, 0, 0, 0);
  }
  #pragma unroll
  for (int r=0;r<4;++r){
    po[wv*512 + (quad*4+r)*32 +      r16] = oa0[r];
    po[wv*512 + (quad*4+r)*32 + 16 + r16] = oa1[r];
  }
  __syncthreads();
  if (t < 256){
    int e = t*2;
    float v0 = 0.f, v1 = 0.f;
    #pragma unroll
    for (int w=0;w<8;++w){ v0 += po[w*512 + e]; v1 += po[w*512 + e + 1]; }
    int q = e>>5, d = e&31;
    int b = bh>>3, hh = bh&7;
    size_t off = ((size_t)(b*1024 + qt*16 + q))*256 + hh*32 + d;
    *(unsigned*)(ob + off) = pk2bf(v0, v1);
  }
}

// ---------------- Volatilite: f *= std_L(f), in place (bf16) ----------------
__global__ __launch_bounds__(512) void vol_scale(short* __restrict__ f)
{
  __shared__ float ps[8][64], pq[8][64], vs[64];
  int b = blockIdx.x >> 4, cb = blockIdx.x & 15;
  int cl = threadIdx.x & 63, sl = threadIdx.x >> 6;   // 8 waves x 128 L each
  int col = cb*64 + cl;
  short* fb = f + (size_t)b*L_*DFF + col;
  float s = 0.f, sq = 0.f;
  for (int l = sl*128; l < sl*128+128; ++l){
    float v = bf2f(fb[(size_t)l*DFF]);
    s += v; sq += v*v;
  }
  ps[sl][cl] = s; pq[sl][cl] = sq;
  __syncthreads();
  if (threadIdx.x < 64){
    float st=0.f, qt=0.f;
    #pragma unroll
    for (int i=0;i<8;++i){ st += ps[i][cl]; qt += pq[i][cl]; }
    float mean = st*(1.f/L_);
    float var  = qt*(1.f/L_) - mean*mean;
    vs[cl] = sqrtf(fmaxf(var, 0.f));
  }
  __syncthreads();
  float vv = vs[cl];
  for (int l = sl*128; l < sl*128+128; ++l){
    size_t o = (size_t)l*DFF;
    fb[o] = f2bf(bf2f(fb[o]) * vv);
  }
}

// ---------------- launch ----------------
extern "C" void kernel_launch(void* const* d_in, const int* in_sizes, int n_in,
                              void* d_out, int out_size, void* d_ws, size_t ws_size,
                              hipStream_t stream) {
  const float* x     = (const float*)d_in[0];
  const float* in_w  = (const float*)d_in[1];
  const float* in_b  = (const float*)d_in[2];
  const float* ln1_g = (const float*)d_in[3];
  const float* ln1_b = (const float*)d_in[4];
  const float* qkv_w = (const float*)d_in[5];
  const float* qkv_b = (const float*)d_in[6];
  const float* out_w = (const float*)d_in[7];
  const float* out_b = (const float*)d_in[8];
  const float* lna_g = (const float*)d_in[9];
  const float* lna_b = (const float*)d_in[10];
  const float* ln2_g = (const float*)d_in[11];
  const float* ln2_b = (const float*)d_in[12];
  const float* ff1_w = (const float*)d_in[13];
  const float* ff1_b = (const float*)d_in[14];
  const float* ff2_w = (const float*)d_in[15];
  const float* ff2_b = (const float*)d_in[16];
  const float* lnf_g = (const float*)d_in[17];
  const float* lnf_b = (const float*)d_in[18];
  float* out = (float*)d_out;

  // ws layout (~37.6 MB):
  //  h @0 8M | s2b @8M 4M | qkbf @12M 8M | vTb @20M 4M | ob_b @24M 4M
  //  f @12M 16M (aliases qkbf/vTb/ob_b — dead at ff1 time) | tb @28M 8M
  //  weights @36M: qkv 384K + out 128K + ff1 512K + ff2 512K
  char* ws = (char*)d_ws;
  float* h     = (float*)(ws);
  short* s2b   = (short*)(ws + (size_t)( 8<<20));
  short* qkbf  = (short*)(ws + (size_t)(12<<20));
  short* vTb   = (short*)(ws + (size_t)(20<<20));
  short* ob_b  = (short*)(ws + (size_t)(24<<20));
  short* f     = (short*)(ws + (size_t)(12<<20));
  float* tb    = (float*)(ws + (size_t)(28<<20));
  short* qkvwT = (short*)(ws + (size_t)(36<<20));
  short* outwT = (short*)(ws + (size_t)(36<<20) + 393216);
  short* ff1wT = (short*)(ws + (size_t)(36<<20) + 393216 + 131072);
  short* ff2wT = (short*)(ws + (size_t)(36<<20) + 393216 + 131072 + 524288);

  embed_kernel<<<NR*64/256, 256, 0, stream>>>(x, in_w, in_b, h);
  wcvt<<< 768, 256, 0, stream>>>(qkv_w, qkvwT,  768, 8);
  wcvt<<< 256, 256, 0, stream>>>(out_w, outwT,  256, 8);
  wcvt<<<1024, 256, 0, stream>>>(ff1_w, ff1wT, 1024, 8);
  wcvt<<<1024, 256, 0, stream>>>(ff2_w, ff2wT,  256, 10);

  for (int layer = 0; layer < NLAYERS; ++layer){
    // s2b = bf16(LN1(h))
    ln_kernel<2><<<NR/4, 256, 0, stream>>>(h, ln1_g, ln1_b, nullptr, s2b);
    // qkv GEMM -> bf16 Q,K row-major + bf16 V^T
    {
      dim3 g(768/64, NR/128);
      mfma_gemm<0><<<g, 256, 0, stream>>>(s2b, qkvwT, qkv_b, nullptr,
                                          nullptr, qkbf, vTb, 768, 256);
    }
    // ProbSparse attention -> ob bf16
    attn_mfma<<<64*64, 512, 0, stream>>>(qkbf, vTb, ob_b);
    // tb = ob @ out_w + out_b + s2 (fp32)
    {
      dim3 g(256/64, NR/128);
      mfma_gemm<1><<<g, 256, 0, stream>>>(ob_b, outwT, out_b, s2b,
                                          tb, nullptr, nullptr, 256, 256);
    }
    // h += LN_a(tb); s2b = bf16(LN_2(h))
    lnln_kernel<<<NR/4, 256, 0, stream>>>(tb, lna_g, lna_b, ln2_g, ln2_b, h, s2b);
    // f = bf16(s2 @ ff1_w + ff1_b)
    {
      dim3 g(1024/64, NR/128);
      mfma_gemm<2><<<g, 256, 0, stream>>>(s2b, ff1wT, ff1_b, nullptr,
                                          nullptr, f, nullptr, 1024, 256);
    }
    // f *= std_L(f) in place
    vol_scale<<<B_*16, 512, 0, stream>>>(f);
    // h += f @ ff2_w + ff2_b
    {
      dim3 g(256/64, NR/128);
      mfma_gemm<3><<<g, 256, 0, stream>>>(f, ff2wT, ff2_b, nullptr,
                                          h, nullptr, nullptr, 256, 1024);
    }
  }
  // out = LN_f(h)
  ln_kernel<0><<<NR/4, 256, 0, stream>>>(h, lnf_g, lnf_b, out, nullptr);
}

// Round 9
// 1166.027 us; speedup vs baseline: 1.3458x; 1.0124x over previous
//
#include <hip/hip_runtime.h>
#include <hip/hip_bf16.h>
#include <math.h>

#define D_MODEL 256
#define NH 8
#define DFF 1024
#define NLAYERS 6
#define B_ 8
#define L_ 1024
#define NR (B_*L_)          // 8192 rows
#define TOPK 256            // L/4
#define LNEPS 1e-5f

typedef __attribute__((ext_vector_type(8))) short bf16x8;
typedef __attribute__((ext_vector_type(4))) float f32x4;

// ---------------- helpers ----------------
__device__ __forceinline__ float wsum(float v){
  #pragma unroll
  for(int o=32;o>0;o>>=1) v += __shfl_xor(v,o,64);
  return v;
}
__device__ __forceinline__ short f2bf(float x){
  unsigned u = __float_as_uint(x);
  u += 0x7fffu + ((u>>16)&1u);   // RNE (finite inputs only)
  return (short)(u>>16);
}
__device__ __forceinline__ float bf2f(short s){
  return __uint_as_float(((unsigned)(unsigned short)s)<<16);
}
// packed 2x f32 -> 2x bf16 (v_cvt_pk_bf16_f32)
__device__ __forceinline__ unsigned pk2bf(float a, float b){
  __hip_bfloat162 h = __float22bfloat162_rn(make_float2(a,b));
  unsigned u; __builtin_memcpy(&u, &h, 4);
  return u;
}
// sortable 16-bit key -> float value (uniform use -> SALU)
__device__ __forceinline__ float kinvf(int k){
  unsigned u = (k & 0x8000) ? ((unsigned)k ^ 0x8000u) : ((unsigned)k ^ 0xFFFFu);
  return __uint_as_float(u << 16);
}
// async global->LDS, 16B per lane (dest = wave-uniform base + lane*16)
__device__ __forceinline__ void g2l(const short* g, short* l){
  __builtin_amdgcn_global_load_lds(
      (const __attribute__((address_space(1))) unsigned int*)g,
      (__attribute__((address_space(3))) unsigned int*)l,
      16, 0, 0);
}

// ---------------- embed: h = x@in_w + in_b + pe ----------------
__global__ __launch_bounds__(256) void embed_kernel(
    const float* __restrict__ x, const float* __restrict__ in_w,
    const float* __restrict__ in_b, float* __restrict__ h)
{
  int tid = blockIdx.x*256 + threadIdx.x;
  int n  = tid >> 6;
  int d0 = (tid & 63) << 2;
  int l  = n & (L_-1);
  float x0 = x[2*n], x1 = x[2*n+1];
  const float kf = -0.07195578415606394f;   // -ln(10000)/128
  float pe[4];
  #pragma unroll
  for(int ii=0; ii<2; ++ii){
    int i = (d0>>1) + ii;
    float dv  = expf((float)i * kf);
    float ang = (float)l * dv;
    pe[2*ii]   = sinf(ang);
    pe[2*ii+1] = cosf(ang);
  }
  float4 w0 = *(const float4*)(in_w + d0);
  float4 w1 = *(const float4*)(in_w + D_MODEL + d0);
  float4 bb = *(const float4*)(in_b + d0);
  float4 o;
  o.x = x0*w0.x + x1*w1.x + bb.x + pe[0];
  o.y = x0*w0.y + x1*w1.y + bb.y + pe[1];
  o.z = x0*w0.z + x1*w1.z + bb.z + pe[2];
  o.w = x0*w0.w + x1*w1.w + bb.w + pe[3];
  *(float4*)(h + (size_t)n*D_MODEL + d0) = o;
}

// ---------------- weight convert+transpose: WT[n][k] = bf16(W[k][n]) ----------------
__global__ __launch_bounds__(256) void wcvt(
    const float* __restrict__ W, short* __restrict__ WT, int N, int kshift)
{
  int idx = blockIdx.x*256 + threadIdx.x;
  int K = 1<<kshift;
  if (idx >= N*K) return;
  int n = idx >> kshift, k = idx & (K-1);
  WT[idx] = f2bf(W[(size_t)k*N + n]);
}

// ---------------- LayerNorm: wave per row ----------------
// OM: 0 = fp32 out, 2 = bf16 out only
template<int OM>
__global__ __launch_bounds__(256) void ln_kernel(
    const float* __restrict__ in, const float* __restrict__ g,
    const float* __restrict__ b, float* __restrict__ out,
    short* __restrict__ outb)
{
  int wave = threadIdx.x >> 6, lane = threadIdx.x & 63;
  int row = blockIdx.x*4 + wave;
  float4 v = ((const float4*)(in + (size_t)row*D_MODEL))[lane];
  float s  = v.x+v.y+v.z+v.w;
  float sq = v.x*v.x+v.y*v.y+v.z*v.z+v.w*v.w;
  s = wsum(s); sq = wsum(sq);
  float mean = s*(1.f/D_MODEL);
  float var  = sq*(1.f/D_MODEL) - mean*mean;
  float rstd = 1.f/sqrtf(var + LNEPS);
  float4 gv = ((const float4*)g)[lane];
  float4 bv = ((const float4*)b)[lane];
  float4 o;
  o.x = (v.x-mean)*rstd*gv.x + bv.x;
  o.y = (v.y-mean)*rstd*gv.y + bv.y;
  o.z = (v.z-mean)*rstd*gv.z + bv.z;
  o.w = (v.w-mean)*rstd*gv.w + bv.w;
  if (OM == 0){
    ((float4*)(out + (size_t)row*D_MODEL))[lane] = o;
  }
  if (OM == 2){
    uint2 pk; pk.x = pk2bf(o.x, o.y); pk.y = pk2bf(o.z, o.w);
    *(uint2*)(outb + (size_t)row*D_MODEL + lane*4) = pk;
  }
}

// ---------------- fused: h += LN_a(tb); s2b = bf16(LN_2(h)) ----------------
__global__ __launch_bounds__(256) void lnln_kernel(
    const float* __restrict__ tb,
    const float* __restrict__ ga, const float* __restrict__ ba,
    const float* __restrict__ g2, const float* __restrict__ b2,
    float* __restrict__ h, short* __restrict__ s2b)
{
  int wave = threadIdx.x >> 6, lane = threadIdx.x & 63;
  int row = blockIdx.x*4 + wave;
  float4 v = ((const float4*)(tb + (size_t)row*D_MODEL))[lane];
  float s  = v.x+v.y+v.z+v.w;
  float sq = v.x*v.x+v.y*v.y+v.z*v.z+v.w*v.w;
  s = wsum(s); sq = wsum(sq);
  float mean = s*(1.f/D_MODEL);
  float var  = sq*(1.f/D_MODEL) - mean*mean;
  float rstd = 1.f/sqrtf(var + LNEPS);
  float4 gv = ((const float4*)ga)[lane];
  float4 bv = ((const float4*)ba)[lane];
  float4* hp = (float4*)(h + (size_t)row*D_MODEL) + lane;
  float4 hv = *hp;
  float4 hn;
  hn.x = hv.x + (v.x-mean)*rstd*gv.x + bv.x;
  hn.y = hv.y + (v.y-mean)*rstd*gv.y + bv.y;
  hn.z = hv.z + (v.z-mean)*rstd*gv.z + bv.z;
  hn.w = hv.w + (v.w-mean)*rstd*gv.w + bv.w;
  *hp = hn;
  float s2  = hn.x+hn.y+hn.z+hn.w;
  float sq2 = hn.x*hn.x+hn.y*hn.y+hn.z*hn.z+hn.w*hn.w;
  s2 = wsum(s2); sq2 = wsum(sq2);
  float m2 = s2*(1.f/D_MODEL);
  float v2 = sq2*(1.f/D_MODEL) - m2*m2;
  float r2 = 1.f/sqrtf(v2 + LNEPS);
  float4 g2v = ((const float4*)g2)[lane];
  float4 b2v = ((const float4*)b2)[lane];
  uint2 pk;
  pk.x = pk2bf((hn.x-m2)*r2*g2v.x + b2v.x, (hn.y-m2)*r2*g2v.y + b2v.y);
  pk.y = pk2bf((hn.z-m2)*r2*g2v.z + b2v.z, (hn.w-m2)*r2*g2v.w + b2v.w);
  *(uint2*)(s2b + (size_t)row*D_MODEL + lane*4) = pk;
}

// ---------------- bf16 MFMA GEMM: 128x64 tile, BK=32 (measured-best) ----------------
// MODE 0: qkv epilogue (Q/K row-major bf16 + V^T bf16)
// MODE 1: Cf = acc + bias + bf2f(residb)    (fp32 out)
// MODE 2: Cb = bf16(acc + bias)
// MODE 3: Cf += acc + bias                  (fp32 accumulate into h)
template<int MODE>
__global__ __launch_bounds__(256) void mfma_gemm(
    const short* __restrict__ A, const short* __restrict__ BT,
    const float* __restrict__ bias, const short* __restrict__ residb,
    float* __restrict__ Cf, short* __restrict__ Cb, short* __restrict__ Vt,
    int N, int K)
{
  __shared__ __align__(16) short As[128*32];   // 8 KB [m][k]
  __shared__ __align__(16) short Bs[64*32];    // 4 KB [n][k]
  const int t = threadIdx.x, wv = t>>6, lane = t&63;
  const int r16 = lane&15, quad = lane>>4;
  const int m0 = blockIdx.y*128, n0 = blockIdx.x*64;
  const int ia0 = wv*128 + lane, ia1 = ia0 + 64;
  const int ib  = wv*64 + lane;
  const short* Ab = A  + (size_t)m0*K;
  const short* Bb = BT + (size_t)n0*K;
  const f32x4 z = {0.f,0.f,0.f,0.f};
  f32x4 acc[2][4];
  #pragma unroll
  for (int i=0;i<2;++i)
    #pragma unroll
    for (int j=0;j<4;++j) acc[i][j] = z;

  for (int k0 = 0; k0 < K; k0 += 32){
    __syncthreads();
    g2l(Ab + (size_t)(ia0>>2)*K + k0 + (ia0&3)*8, As + ia0*8);
    g2l(Ab + (size_t)(ia1>>2)*K + k0 + (ia1&3)*8, As + ia1*8);
    g2l(Bb + (size_t)(ib>>2)*K  + k0 + (ib&3)*8,  Bs + ib*8);
    __syncthreads();
    bf16x8 af0 = *(const bf16x8*)(As + ((wv*32      + r16)*32 + quad*8));
    bf16x8 af1 = *(const bf16x8*)(As + ((wv*32 + 16 + r16)*32 + quad*8));
    bf16x8 bf[4];
    #pragma unroll
    for (int ct=0; ct<4; ++ct)
      bf[ct] = *(const bf16x8*)(Bs + ((ct*16 + r16)*32 + quad*8));
    #pragma unroll
    for (int ct=0; ct<4; ++ct){
      acc[0][ct] = __builtin_amdgcn_mfma_f32_16x16x32_bf16(af0, bf[ct], acc[0][ct], 0,0,0);
      acc[1][ct] = __builtin_amdgcn_mfma_f32_16x16x32_bf16(af1, bf[ct], acc[1][ct], 0,0,0);
    }
  }

  #pragma unroll
  for (int rt=0; rt<2; ++rt){
    const int mb = m0 + wv*32 + rt*16 + quad*4;
    #pragma unroll
    for (int ct=0; ct<4; ++ct){
      const int n = n0 + ct*16 + r16;
      const float bv = bias[n];
      if (MODE == 0){
        if (n < 512){                    // Q or K: qkbf[region*64+bh][l][d]
          int region = n>>8, hh = (n>>5)&7, d = n&31;
          #pragma unroll
          for (int r=0;r<4;++r){
            int l = mb + r;
            size_t base = (((size_t)(region*64 + (l>>10)*8 + hh))*1024 + (l&1023))*32 + d;
            Cb[base] = f2bf(acc[rt][ct][r] + bv);
          }
        } else {                         // V transposed: vT[bh][d][l]
          int dv = n - 512, hh = dv>>5, d = dv&31;
          int b = mb>>10, lloc = mb&1023;
          size_t base = (((size_t)(b*8 + hh))*32 + d)*1024 + lloc;
          uint2 pk;
          pk.x = pk2bf(acc[rt][ct][0] + bv, acc[rt][ct][1] + bv);
          pk.y = pk2bf(acc[rt][ct][2] + bv, acc[rt][ct][3] + bv);
          *(uint2*)(Vt + base) = pk;
        }
      } else {
        #pragma unroll
        for (int r=0;r<4;++r){
          size_t off = (size_t)(mb + r)*N + n;
          float c = acc[rt][ct][r] + bv;
          if (MODE == 1) Cf[off] = c + bf2f(residb[off]);
          if (MODE == 2) Cb[off] = f2bf(c);
          if (MODE == 3) Cf[off] += c;
        }
      }
    }
  }
}

// ---------------- MFMA ProbSparse attention v7: 8 waves, 40 KB LDS ----------------
// Block = (bh, 16 q rows), 512 threads. QK: 8 key-tiles/wave. Selection:
// 2 rows/wave, single-pass float-domain 16-step bit-descent. PV split by
// DIM-HALF: waves 0-3 compute dims 0-15 (256 keys each), waves 4-7 dims
// 16-31 -> po is 8 KB (one 16x16 tile per wave, partial depth 4).
// LDS = 32 KB scores + 8 KB po = 40 KB -> 4 blocks x 8 waves = 32 waves/CU.
__global__ __launch_bounds__(512,8) void attn_mfma(
    const short* __restrict__ qkbf, const short* __restrict__ vT,
    short* __restrict__ ob)
{
  __shared__ __align__(16) short sc16[16*1024];   // 32 KB scores/weights
  __shared__ __align__(16) float po[8*256];       // 8 KB O partials
  const int t = threadIdx.x, wv = t>>6, lane = t&63;
  const int r16 = lane&15, quad = lane>>4;
  const int blk = blockIdx.x;
  const int bh = (blk & 7)*8 + ((blk>>3)&7);   // head pinned to one XCD
  const int qt = blk >> 6;

  bf16x8 aq = *(const bf16x8*)(qkbf + ((size_t)bh*1024 + qt*16 + r16)*32 + quad*8);
  const short* kb = qkbf + (size_t)(64 + bh)*1024*32;
  short* p0 = sc16 + quad*4096;        // rows quad*4..quad*4+3

  // ---- QK: 8 key-tiles per wave (keys wv*128..+127) ----
  #pragma unroll
  for (int g=0; g<2; ++g){
    bf16x8 bkb[4];
    #pragma unroll
    for (int j=0;j<4;++j)
      bkb[j] = *(const bf16x8*)(kb + (size_t)(wv*128 + (g*4+j)*16 + r16)*32 + quad*8);
    #pragma unroll
    for (int j=0;j<4;++j){
      f32x4 c = {0.f,0.f,0.f,0.f};
      c = __builtin_amdgcn_mfma_f32_16x16x32_bf16(aq, bkb[j], c, 0, 0, 0);
      const int keyq = (wv*128 + (g*4+j)*16 + r16) ^ ((quad&1)<<5);
      unsigned u01 = pk2bf(c[0], c[1]);
      unsigned u23 = pk2bf(c[2], c[3]);
      p0[keyq]               = (short)u01;          // r=0
      p0[1024 + (keyq ^ 8)]  = (short)(u01>>16);    // r=1
      p0[2048 + (keyq ^ 16)] = (short)u23;          // r=2
      p0[3072 + (keyq ^ 24)] = (short)(u23>>16);    // r=3
    }
  }
  __syncthreads();

  // ---- selection + softmax: wave wv owns rows 2wv, 2wv+1 (one pass) ----
  const float SC2 = 0.25500529485087056f;   // (1/sqrt(32)) * log2(e)
  {
    const int ra = wv*2;
    const int sa = (ra&7)<<3;                 // ra even
    short* pa = sc16 + ra*1024 + ((2*lane) ^ sa);
    short* pb = sc16 + (ra+1)*1024 + (((2*lane) ^ sa) ^ 8);
    float fa[16], fb[16];
    #pragma unroll
    for (int i=0;i<8;++i){
      unsigned wa = *(const unsigned*)(pa + i*128);
      unsigned wb = *(const unsigned*)(pb + i*128);
      fa[2*i]   = __uint_as_float(wa << 16);
      fa[2*i+1] = __uint_as_float(wa & 0xFFFF0000u);
      fb[2*i]   = __uint_as_float(wb << 16);
      fb[2*i+1] = __uint_as_float(wb & 0xFFFF0000u);
    }
    // fixed 16-step bit-descent over sortable-int candidates, float compares
    int loA = 0, loB = 0;
    #pragma unroll
    for (int bit = 15; bit >= 0; --bit){
      const int mA = loA | (1<<bit);
      const int mB = loB | (1<<bit);
      const float tA = kinvf(mA);   // wave-uniform -> SALU
      const float tB = kinvf(mB);
      int cA = 0, cB = 0;
      #pragma unroll
      for (int i=0;i<16;++i){
        cA += (int)__popcll(__ballot(fa[i] >= tA));
        cB += (int)__popcll(__ballot(fb[i] >= tB));
      }
      if (cA >= TOPK) loA = mA;
      if (cB >= TOPK) loB = mB;
    }
    const float thrA = kinvf(loA), thrB = kinvf(loB);
    float ea[16], eb[16];
    float suma = 0.f, sumb = 0.f;
    #pragma unroll
    for (int i=0;i<16;++i){
      ea[i] = (fa[i] >= thrA) ? exp2f(fa[i]*SC2) : 0.f;
      eb[i] = (fb[i] >= thrB) ? exp2f(fb[i]*SC2) : 0.f;
      suma += ea[i]; sumb += eb[i];
    }
    suma = wsum(suma); sumb = wsum(sumb);
    const float inva = 1.f/suma, invb = 1.f/sumb;
    #pragma unroll
    for (int i=0;i<8;++i){
      *(unsigned*)(pa + i*128) = pk2bf(ea[2*i]*inva, ea[2*i+1]*inva);
      *(unsigned*)(pb + i*128) = pk2bf(eb[2*i]*invb, eb[2*i+1]*invb);
    }
  }
  __syncthreads();

  // ---- PV: wave wv -> dim-half wv>>2 (16 dims), key-slice (wv&3)*256 ----
  const int dh = wv>>2, ks = (wv&3)*256;
  const short* vb = vT + (size_t)bh*32*1024 + (size_t)(dh*16 + r16)*1024;
  const int sA = (r16&7) << 3;         // s(row=r16)
  f32x4 oa = {0.f,0.f,0.f,0.f};
  #pragma unroll
  for (int j=0;j<8;++j){
    int k0 = ks + j*32;
    bf16x8 bv = *(const bf16x8*)(vb + k0 + quad*8);
    bf16x8 af = *(const bf16x8*)(sc16 + r16*1024 + ((k0 + quad*8) ^ sA));
    oa = __builtin_amdgcn_mfma_f32_16x16x32_bf16(af, bv, oa, 0, 0, 0);
  }
  // po is a separate region: no barrier needed between weight reads and writes
  #pragma unroll
  for (int r=0;r<4;++r)
    po[wv*256 + (quad*4+r)*16 + r16] = oa[r];
  __syncthreads();
  if (t < 256){
    int q = t>>4, d = (t&15)*2;        // d even; pair (d,d+1) in same half
    int h4 = (d>>4)*4;
    float v0 = 0.f, v1 = 0.f;
    #pragma unroll
    for (int w=0;w<4;++w){
      v0 += po[(h4+w)*256 + q*16 + (d&15)];
      v1 += po[(h4+w)*256 + q*16 + ((d+1)&15)];
    }
    int b = bh>>3, hh = bh&7;
    size_t off = ((size_t)(b*1024 + qt*16 + q))*256 + hh*32 + d;
    *(unsigned*)(ob + off) = pk2bf(v0, v1);
  }
}

// ---------------- Volatilite: f *= std_L(f), in place (bf16) ----------------
__global__ __launch_bounds__(512) void vol_scale(short* __restrict__ f)
{
  __shared__ float ps[8][64], pq[8][64], vs[64];
  int b = blockIdx.x >> 4, cb = blockIdx.x & 15;
  int cl = threadIdx.x & 63, sl = threadIdx.x >> 6;   // 8 waves x 128 L each
  int col = cb*64 + cl;
  short* fb = f + (size_t)b*L_*DFF + col;
  float s = 0.f, sq = 0.f;
  for (int l = sl*128; l < sl*128+128; ++l){
    float v = bf2f(fb[(size_t)l*DFF]);
    s += v; sq += v*v;
  }
  ps[sl][cl] = s; pq[sl][cl] = sq;
  __syncthreads();
  if (threadIdx.x < 64){
    float st=0.f, qt=0.f;
    #pragma unroll
    for (int i=0;i<8;++i){ st += ps[i][cl]; qt += pq[i][cl]; }
    float mean = st*(1.f/L_);
    float var  = qt*(1.f/L_) - mean*mean;
    vs[cl] = sqrtf(fmaxf(var, 0.f));
  }
  __syncthreads();
  float vv = vs[cl];
  for (int l = sl*128; l < sl*128+128; ++l){
    size_t o = (size_t)l*DFF;
    fb[o] = f2bf(bf2f(fb[o]) * vv);
  }
}

// ---------------- launch ----------------
extern "C" void kernel_launch(void* const* d_in, const int* in_sizes, int n_in,
                              void* d_out, int out_size, void* d_ws, size_t ws_size,
                              hipStream_t stream) {
  const float* x     = (const float*)d_in[0];
  const float* in_w  = (const float*)d_in[1];
  const float* in_b  = (const float*)d_in[2];
  const float* ln1_g = (const float*)d_in[3];
  const float* ln1_b = (const float*)d_in[4];
  const float* qkv_w = (const float*)d_in[5];
  const float* qkv_b = (const float*)d_in[6];
  const float* out_w = (const float*)d_in[7];
  const float* out_b = (const float*)d_in[8];
  const float* lna_g = (const float*)d_in[9];
  const float* lna_b = (const float*)d_in[10];
  const float* ln2_g = (const float*)d_in[11];
  const float* ln2_b = (const float*)d_in[12];
  const float* ff1_w = (const float*)d_in[13];
  const float* ff1_b = (const float*)d_in[14];
  const float* ff2_w = (const float*)d_in[15];
  const float* ff2_b = (const float*)d_in[16];
  const float* lnf_g = (const float*)d_in[17];
  const float* lnf_b = (const float*)d_in[18];
  float* out = (float*)d_out;

  // ws layout (~37.6 MB):
  //  h @0 8M | s2b @8M 4M | qkbf @12M 8M | vTb @20M 4M | ob_b @24M 4M
  //  f @12M 16M (aliases qkbf/vTb/ob_b — dead at ff1 time) | tb @28M 8M
  //  weights @36M: qkv 384K + out 128K + ff1 512K + ff2 512K
  char* ws = (char*)d_ws;
  float* h     = (float*)(ws);
  short* s2b   = (short*)(ws + (size_t)( 8<<20));
  short* qkbf  = (short*)(ws + (size_t)(12<<20));
  short* vTb   = (short*)(ws + (size_t)(20<<20));
  short* ob_b  = (short*)(ws + (size_t)(24<<20));
  short* f     = (short*)(ws + (size_t)(12<<20));
  float* tb    = (float*)(ws + (size_t)(28<<20));
  short* qkvwT = (short*)(ws + (size_t)(36<<20));
  short* outwT = (short*)(ws + (size_t)(36<<20) + 393216);
  short* ff1wT = (short*)(ws + (size_t)(36<<20) + 393216 + 131072);
  short* ff2wT = (short*)(ws + (size_t)(36<<20) + 393216 + 131072 + 524288);

  embed_kernel<<<NR*64/256, 256, 0, stream>>>(x, in_w, in_b, h);
  wcvt<<< 768, 256, 0, stream>>>(qkv_w, qkvwT,  768, 8);
  wcvt<<< 256, 256, 0, stream>>>(out_w, outwT,  256, 8);
  wcvt<<<1024, 256, 0, stream>>>(ff1_w, ff1wT, 1024, 8);
  wcvt<<<1024, 256, 0, stream>>>(ff2_w, ff2wT,  256, 10);

  for (int layer = 0; layer < NLAYERS; ++layer){
    // s2b = bf16(LN1(h))
    ln_kernel<2><<<NR/4, 256, 0, stream>>>(h, ln1_g, ln1_b, nullptr, s2b);
    // qkv GEMM -> bf16 Q,K row-major + bf16 V^T
    {
      dim3 g(768/64, NR/128);
      mfma_gemm<0><<<g, 256, 0, stream>>>(s2b, qkvwT, qkv_b, nullptr,
                                          nullptr, qkbf, vTb, 768, 256);
    }
    // ProbSparse attention -> ob bf16
    attn_mfma<<<64*64, 512, 0, stream>>>(qkbf, vTb, ob_b);
    // tb = ob @ out_w + out_b + s2 (fp32)
    {
      dim3 g(256/64, NR/128);
      mfma_gemm<1><<<g, 256, 0, stream>>>(ob_b, outwT, out_b, s2b,
                                          tb, nullptr, nullptr, 256, 256);
    }
    // h += LN_a(tb); s2b = bf16(LN_2(h))
    lnln_kernel<<<NR/4, 256, 0, stream>>>(tb, lna_g, lna_b, ln2_g, ln2_b, h, s2b);
    // f = bf16(s2 @ ff1_w + ff1_b)
    {
      dim3 g(1024/64, NR/128);
      mfma_gemm<2><<<g, 256, 0, stream>>>(s2b, ff1wT, ff1_b, nullptr,
                                          nullptr, f, nullptr, 1024, 256);
    }
    // f *= std_L(f) in place
    vol_scale<<<B_*16, 512, 0, stream>>>(f);
    // h += f @ ff2_w + ff2_b
    {
      dim3 g(256/64, NR/128);
      mfma_gemm<3><<<g, 256, 0, stream>>>(f, ff2wT, ff2_b, nullptr,
                                          h, nullptr, nullptr, 256, 1024);
    }
  }
  // out = LN_f(h)
  ln_kernel<0><<<NR/4, 256, 0, stream>>>(h, lnf_g, lnf_b, out, nullptr);
}